// Round 1
// baseline (241.871 us; speedup 1.0000x reference)
//
#include <hip/hip_runtime.h>
#include <hip/hip_bf16.h>

typedef unsigned short u16;
typedef short short8 __attribute__((ext_vector_type(8)));
typedef float floatx4 __attribute__((ext_vector_type(4)));

#define NNODES 2048
#define BATCH  64
#define DIN    64
#define DOUT   64
#define EMB    16

__device__ __forceinline__ u16 f2bf(float f) {
  union { float f; unsigned u; } v; v.f = f;
  unsigned r = v.u + 0x7fffu + ((v.u >> 16) & 1u);
  return (u16)(r >> 16);
}

__device__ __forceinline__ void gload_lds16(const void* g, void* l) {
  __builtin_amdgcn_global_load_lds(
      (const __attribute__((address_space(1))) void*)g,
      (__attribute__((address_space(3))) void*)l, 16, 0, 0);
}

// ---------------------------------------------------------------------------
// S = softmax(relu(E E^T), axis=1), output bf16 (2048 x 2048)
// one block per row n
// ---------------------------------------------------------------------------
__global__ __launch_bounds__(256) void adj_softmax(const float* __restrict__ E,
                                                   u16* __restrict__ Sb) {
  int n = blockIdx.x, t = threadIdx.x;
  const float4* ep = (const float4*)(E + (size_t)n * EMB);
  float4 e0 = ep[0], e1 = ep[1], e2 = ep[2], e3 = ep[3];

  float lg[8];
  float mx = 0.0f;  // relu => all logits >= 0
#pragma unroll
  for (int j = 0; j < 8; j++) {
    int m = t + j * 256;
    const float4* mp = (const float4*)(E + (size_t)m * EMB);
    float4 a = mp[0], b = mp[1], c = mp[2], d = mp[3];
    float dot = e0.x * a.x + e0.y * a.y + e0.z * a.z + e0.w * a.w
              + e1.x * b.x + e1.y * b.y + e1.z * b.z + e1.w * b.w
              + e2.x * c.x + e2.y * c.y + e2.z * c.z + e2.w * c.w
              + e3.x * d.x + e3.y * d.y + e3.z * d.z + e3.w * d.w;
    dot = fmaxf(dot, 0.0f);
    lg[j] = dot;
    mx = fmaxf(mx, dot);
  }
  __shared__ float smax[4], ssum[4];
#pragma unroll
  for (int off = 32; off > 0; off >>= 1) mx = fmaxf(mx, __shfl_xor(mx, off, 64));
  if ((t & 63) == 0) smax[t >> 6] = mx;
  __syncthreads();
  mx = fmaxf(fmaxf(smax[0], smax[1]), fmaxf(smax[2], smax[3]));

  float sum = 0.0f;
#pragma unroll
  for (int j = 0; j < 8; j++) {
    float e = __expf(lg[j] - mx);
    lg[j] = e;
    sum += e;
  }
#pragma unroll
  for (int off = 32; off > 0; off >>= 1) sum += __shfl_xor(sum, off, 64);
  if ((t & 63) == 0) ssum[t >> 6] = sum;
  __syncthreads();
  sum = ssum[0] + ssum[1] + ssum[2] + ssum[3];
  float inv = 1.0f / sum;
#pragma unroll
  for (int j = 0; j < 8; j++) {
    Sb[(size_t)n * NNODES + t + j * 256] = f2bf(lg[j] * inv);
  }
}

// ---------------------------------------------------------------------------
// x (B,N,DIN) f32 -> x_tt (B*DIN, N) bf16 : x_tt[b*64+c][m] = x[b][m][c]
// grid: (N/64, B), 256 threads
// ---------------------------------------------------------------------------
__global__ __launch_bounds__(256) void trans_x(const float* __restrict__ x,
                                               u16* __restrict__ xtt) {
  __shared__ float tile[64][68];
  int b = blockIdx.y;
  int m0 = blockIdx.x * 64;
  int t = threadIdx.x;
  int r = t >> 2, cs = (t & 3) * 16;
  const float* xp = x + ((size_t)b * NNODES + m0 + r) * DIN + cs;
  float4 v0 = ((const float4*)xp)[0];
  float4 v1 = ((const float4*)xp)[1];
  float4 v2 = ((const float4*)xp)[2];
  float4 v3 = ((const float4*)xp)[3];
  *(float4*)&tile[r][cs]      = v0;
  *(float4*)&tile[r][cs + 4]  = v1;
  *(float4*)&tile[r][cs + 8]  = v2;
  *(float4*)&tile[r][cs + 12] = v3;
  __syncthreads();
  int c = t >> 2, ms = (t & 3) * 16;
  short8 o0, o1;
#pragma unroll
  for (int j = 0; j < 8; j++) o0[j] = (short)f2bf(tile[ms + j][c]);
#pragma unroll
  for (int j = 0; j < 8; j++) o1[j] = (short)f2bf(tile[ms + 8 + j][c]);
  u16* op = xtt + ((size_t)b * 64 + c) * NNODES + m0 + ms;
  *(short8*)op = o0;
  *(short8*)(op + 8) = o1;
}

// ---------------------------------------------------------------------------
// bf16 transpose (R x C) -> (C x R), 64x64 tiles. grid: (C/64, R/64)
// ---------------------------------------------------------------------------
__global__ __launch_bounds__(256) void trans_bf(const u16* __restrict__ in,
                                                u16* __restrict__ out,
                                                int R, int C) {
  __shared__ u16 tile[64][72];
  int r0 = blockIdx.y * 64, c0 = blockIdx.x * 64;
  int t = threadIdx.x;
  int r = t >> 2, cs = (t & 3) * 16;
  const u16* ip = in + (size_t)(r0 + r) * C + c0 + cs;
  *(short8*)&tile[r][cs]     = *(const short8*)ip;
  *(short8*)&tile[r][cs + 8] = *(const short8*)(ip + 8);
  __syncthreads();
  int c = t >> 2, ms = (t & 3) * 16;
  short8 o0, o1;
#pragma unroll
  for (int j = 0; j < 8; j++) o0[j] = (short)tile[ms + j][c];
#pragma unroll
  for (int j = 0; j < 8; j++) o1[j] = (short)tile[ms + 8 + j][c];
  u16* op = out + (size_t)(c0 + c) * R + r0 + ms;
  *(short8*)op = o0;
  *(short8*)(op + 8) = o1;
}

// ---------------------------------------------------------------------------
// W_all[n][o][k*64+i] = sum_d E[n][d] * pool_eff[d][k][i][o]  (bf16)
// pool_eff folds T0/T2: k0 -> p0 - p2 ; k2 -> 2*p2
// grid: (12288/256, 2048/32), 256 threads
// ---------------------------------------------------------------------------
__global__ __launch_bounds__(256) void wgen(const float* __restrict__ E,
                                            const float* __restrict__ pool,
                                            u16* __restrict__ W) {
  __shared__ float Es[32][17];
  int t = threadIdx.x;
  int n0 = blockIdx.y * 32;
  for (int idx = t; idx < 32 * EMB; idx += 256)
    Es[idx >> 4][idx & 15] = E[(size_t)(n0 + (idx >> 4)) * EMB + (idx & 15)];

  int e = blockIdx.x * 256 + t;       // e = o*192 + k*64 + i
  int o = e / 192;
  int ki = e - o * 192;
  int k = ki >> 6, i = ki & 63;
  int base = k * 4096 + i * 64 + o;   // pool[d][k][i][o] at d*12288 + base
  float pv[16];
#pragma unroll
  for (int d = 0; d < 16; d++) {
    float p = pool[(size_t)d * 12288 + base];
    if (k == 0) p -= pool[(size_t)d * 12288 + 8192 + i * 64 + o];
    if (k == 2) p += p;
    pv[d] = p;
  }
  __syncthreads();
  for (int nn = 0; nn < 32; nn++) {
    float acc = 0.0f;
#pragma unroll
    for (int d = 0; d < 16; d++) acc = fmaf(Es[nn][d], pv[d], acc);
    W[(size_t)(n0 + nn) * 12288 + e] = f2bf(acc);
  }
}

// ---------------------------------------------------------------------------
// bf16 GEMM, m97 structure: C(MxN) = A(MxK) * Bt(NxK)^T, all row-major bf16.
// 128x128 tile, BK=32, 256 threads (4 waves, 2x2 of 64x64), global_load_lds.
// ---------------------------------------------------------------------------
__global__ __launch_bounds__(256) void gemm_bt(const u16* __restrict__ A,
                                               const u16* __restrict__ Bt,
                                               u16* __restrict__ C,
                                               int M, int Nn, int K) {
  __shared__ u16 As[4096];  // [128][32]
  __shared__ u16 Bs[4096];  // [128][32]
  int t = threadIdx.x, lane = t & 63, wave = t >> 6;
  int m0 = blockIdx.y * 128, n0 = blockIdx.x * 128;
  int c0 = t, c1 = t + 256;
  const u16* ag0 = A + (size_t)(m0 + (c0 >> 2)) * K + (c0 & 3) * 8;
  const u16* ag1 = A + (size_t)(m0 + (c1 >> 2)) * K + (c1 & 3) * 8;
  const u16* bg0 = Bt + (size_t)(n0 + (c0 >> 2)) * K + (c0 & 3) * 8;
  const u16* bg1 = Bt + (size_t)(n0 + (c1 >> 2)) * K + (c1 & 3) * 8;
  u16* lA0 = As + wave * 512;
  u16* lA1 = As + 2048 + wave * 512;
  u16* lB0 = Bs + wave * 512;
  u16* lB1 = Bs + 2048 + wave * 512;

  int wr = wave >> 1, wc = wave & 1;
  int lr = lane & 15, kof = (lane >> 4) * 8;

  floatx4 acc[4][4];
#pragma unroll
  for (int mi = 0; mi < 4; mi++)
#pragma unroll
    for (int ni = 0; ni < 4; ni++) acc[mi][ni] = (floatx4)0.0f;

  for (int kt = 0; kt < K; kt += 32) {
    gload_lds16(ag0 + kt, lA0);
    gload_lds16(ag1 + kt, lA1);
    gload_lds16(bg0 + kt, lB0);
    gload_lds16(bg1 + kt, lB1);
    __syncthreads();  // drains vmcnt(0): staged data visible to all waves
    short8 af[4], bf[4];
#pragma unroll
    for (int mi = 0; mi < 4; mi++)
      af[mi] = *(const short8*)&As[(wr * 64 + mi * 16 + lr) * 32 + kof];
#pragma unroll
    for (int ni = 0; ni < 4; ni++)
      bf[ni] = *(const short8*)&Bs[(wc * 64 + ni * 16 + lr) * 32 + kof];
#pragma unroll
    for (int mi = 0; mi < 4; mi++)
#pragma unroll
      for (int ni = 0; ni < 4; ni++)
        acc[mi][ni] = __builtin_amdgcn_mfma_f32_16x16x32_bf16(af[mi], bf[ni],
                                                              acc[mi][ni], 0, 0, 0);
    __syncthreads();  // protect LDS against next iteration's staging
  }

#pragma unroll
  for (int mi = 0; mi < 4; mi++)
#pragma unroll
    for (int ni = 0; ni < 4; ni++) {
      int row = m0 + wr * 64 + mi * 16 + (lane >> 4) * 4;
      int col = n0 + wc * 64 + ni * 16 + lr;
#pragma unroll
      for (int r = 0; r < 4; r++)
        C[(size_t)(row + r) * Nn + col] = f2bf(acc[mi][ni][r]);
    }
}

// ---------------------------------------------------------------------------
// Final per-node fused GEMM: out[b,n,o] = sum_kk A[b,kk]*Weff[n,kk,o] + bias[n,o]
// A[:,0:64]=bf16(x[:,n,:]), A[:,64:128]=xg1[n], A[:,128:192]=xg2[n]
// one block per node, 256 threads (4 waves, 16 b-rows each)
// ---------------------------------------------------------------------------
__global__ __launch_bounds__(256) void final_k(const float* __restrict__ x,
                                               const float* __restrict__ E,
                                               const float* __restrict__ bpool,
                                               const u16* __restrict__ xg1,
                                               const u16* __restrict__ xg2,
                                               const u16* __restrict__ W,
                                               float* __restrict__ out) {
  __shared__ u16 Xs[3][64][72];   // [k][b][i], +8 pad: 2-way banks only
  __shared__ u16 Ws[64][200];     // [o][k*64+i], +8 pad
  __shared__ float bias_s[64];
  int n = blockIdx.x, t = threadIdx.x;

  {  // stage k=0 slab from fp32 x
    int b = t >> 2, i0 = (t & 3) * 16;
    const float* xp = x + ((size_t)b * NNODES + n) * DIN + i0;
    float4 v0 = ((const float4*)xp)[0];
    float4 v1 = ((const float4*)xp)[1];
    float4 v2 = ((const float4*)xp)[2];
    float4 v3 = ((const float4*)xp)[3];
    u16* d = &Xs[0][b][i0];
    d[0] = f2bf(v0.x); d[1] = f2bf(v0.y); d[2] = f2bf(v0.z); d[3] = f2bf(v0.w);
    d[4] = f2bf(v1.x); d[5] = f2bf(v1.y); d[6] = f2bf(v1.z); d[7] = f2bf(v1.w);
    d[8] = f2bf(v2.x); d[9] = f2bf(v2.y); d[10] = f2bf(v2.z); d[11] = f2bf(v2.w);
    d[12] = f2bf(v3.x); d[13] = f2bf(v3.y); d[14] = f2bf(v3.z); d[15] = f2bf(v3.w);
  }
  for (int idx = t; idx < 512; idx += 256) {  // k=1,2 slabs (rows of xg1/xg2)
    short8 v1 = *(const short8*)(xg1 + (size_t)n * 4096 + idx * 8);
    *(short8*)&Xs[1][idx >> 3][(idx & 7) * 8] = v1;
    short8 v2 = *(const short8*)(xg2 + (size_t)n * 4096 + idx * 8);
    *(short8*)&Xs[2][idx >> 3][(idx & 7) * 8] = v2;
  }
  for (int idx = t; idx < 1536; idx += 256) {  // weights: 24 chunks per o-row
    short8 v = *(const short8*)(W + (size_t)n * 12288 + idx * 8);
    int o = idx / 24, w8 = idx - o * 24;
    *(short8*)&Ws[o][w8 * 8] = v;
  }
  if (t < 64) {
    float acc = 0.0f;
#pragma unroll
    for (int d = 0; d < 16; d++)
      acc = fmaf(E[(size_t)n * EMB + d], bpool[d * 64 + t], acc);
    bias_s[t] = acc;
  }
  __syncthreads();

  int lane = t & 63, wave = t >> 6;
  int lr = lane & 15, lg = lane >> 4;
  int wb = wave * 16;
  floatx4 acc[4];
#pragma unroll
  for (int ot = 0; ot < 4; ot++) acc[ot] = (floatx4)0.0f;

#pragma unroll
  for (int ks = 0; ks < 6; ks++) {
    int kk = ks * 32 + lg * 8;
    short8 a = *(const short8*)&Xs[kk >> 6][wb + lr][kk & 63];
#pragma unroll
    for (int ot = 0; ot < 4; ot++) {
      short8 bb = *(const short8*)&Ws[ot * 16 + lr][kk];
      acc[ot] = __builtin_amdgcn_mfma_f32_16x16x32_bf16(a, bb, acc[ot], 0, 0, 0);
    }
  }
#pragma unroll
  for (int ot = 0; ot < 4; ot++) {
    int o = ot * 16 + lr;
    float bs = bias_s[o];
#pragma unroll
    for (int r = 0; r < 4; r++) {
      int b = wb + lg * 4 + r;
      out[((size_t)b * NNODES + n) * DOUT + o] = acc[ot][r] + bs;
    }
  }
}

// ---------------------------------------------------------------------------
extern "C" void kernel_launch(void* const* d_in, const int* in_sizes, int n_in,
                              void* d_out, int out_size, void* d_ws, size_t ws_size,
                              hipStream_t stream) {
  const float* x     = (const float*)d_in[0];  // (64,2048,64)
  const float* E     = (const float*)d_in[1];  // (2048,16)
  const float* pool  = (const float*)d_in[2];  // (16,3,64,64)
  const float* bpool = (const float*)d_in[3];  // (16,64)
  float* out = (float*)d_out;

  char* ws = (char*)d_ws;
  u16* Sb   = (u16*)(ws);                    // 2048*2048*2  = 8 MiB
  u16* xtt  = (u16*)(ws + 8388608);          // 4096*2048*2  = 16 MiB
  u16* xg1  = (u16*)(ws + 25165824);         // 2048*4096*2
  u16* xg1t = (u16*)(ws + 41943040);         // 4096*2048*2
  u16* xg2  = (u16*)(ws + 58720256);         // 2048*4096*2
  u16* Wall = (u16*)(ws + 75497472);         // 2048*12288*2 = 48 MiB  (end 120 MiB)

  adj_softmax<<<NNODES, 256, 0, stream>>>(E, Sb);
  trans_x<<<dim3(NNODES / 64, BATCH), 256, 0, stream>>>(x, xtt);
  wgen<<<dim3(48, NNODES / 32), 256, 0, stream>>>(E, pool, Wall);
  // xg1[n][b*64+c] = sum_m S[n][m] * x[b][m][c]
  gemm_bt<<<dim3(4096 / 128, NNODES / 128), 256, 0, stream>>>(Sb, xtt, xg1,
                                                              NNODES, 4096, NNODES);
  trans_bf<<<dim3(4096 / 64, NNODES / 64), 256, 0, stream>>>(xg1, xg1t, NNODES, 4096);
  // xg2[n][bc] = sum_m S[n][m] * xg1[m][bc]   (un-scaled; T2 folded into Weff)
  gemm_bt<<<dim3(4096 / 128, NNODES / 128), 256, 0, stream>>>(Sb, xg1t, xg2,
                                                              NNODES, 4096, NNODES);
  final_k<<<NNODES, 256, 0, stream>>>(x, E, bpool, xg1, xg2, Wall, out);
}

// Round 2
// 203.628 us; speedup vs baseline: 1.1878x; 1.1878x over previous
//
#include <hip/hip_runtime.h>
#include <hip/hip_bf16.h>

typedef unsigned short u16;
typedef short short8 __attribute__((ext_vector_type(8)));
typedef float floatx4 __attribute__((ext_vector_type(4)));

#define NNODES 2048
#define BATCH  64
#define DIN    64
#define DOUT   64
#define EMB    16

__device__ __forceinline__ u16 f2bf(float f) {
  union { float f; unsigned u; } v; v.f = f;
  unsigned r = v.u + 0x7fffu + ((v.u >> 16) & 1u);
  return (u16)(r >> 16);
}

__device__ __forceinline__ void gload_lds16(const void* g, void* l) {
  __builtin_amdgcn_global_load_lds(
      (const __attribute__((address_space(1))) void*)g,
      (__attribute__((address_space(3))) void*)l, 16, 0, 0);
}

// ---------------------------------------------------------------------------
// S = softmax(relu(E E^T), axis=1), output bf16 (2048 x 2048)
// one block per row n
// ---------------------------------------------------------------------------
__global__ __launch_bounds__(256) void adj_softmax(const float* __restrict__ E,
                                                   u16* __restrict__ Sb) {
  int n = blockIdx.x, t = threadIdx.x;
  const float4* ep = (const float4*)(E + (size_t)n * EMB);
  float4 e0 = ep[0], e1 = ep[1], e2 = ep[2], e3 = ep[3];

  float lg[8];
  float mx = 0.0f;  // relu => all logits >= 0
#pragma unroll
  for (int j = 0; j < 8; j++) {
    int m = t + j * 256;
    const float4* mp = (const float4*)(E + (size_t)m * EMB);
    float4 a = mp[0], b = mp[1], c = mp[2], d = mp[3];
    float dot = e0.x * a.x + e0.y * a.y + e0.z * a.z + e0.w * a.w
              + e1.x * b.x + e1.y * b.y + e1.z * b.z + e1.w * b.w
              + e2.x * c.x + e2.y * c.y + e2.z * c.z + e2.w * c.w
              + e3.x * d.x + e3.y * d.y + e3.z * d.z + e3.w * d.w;
    dot = fmaxf(dot, 0.0f);
    lg[j] = dot;
    mx = fmaxf(mx, dot);
  }
  __shared__ float smax[4], ssum[4];
#pragma unroll
  for (int off = 32; off > 0; off >>= 1) mx = fmaxf(mx, __shfl_xor(mx, off, 64));
  if ((t & 63) == 0) smax[t >> 6] = mx;
  __syncthreads();
  mx = fmaxf(fmaxf(smax[0], smax[1]), fmaxf(smax[2], smax[3]));

  float sum = 0.0f;
#pragma unroll
  for (int j = 0; j < 8; j++) {
    float e = __expf(lg[j] - mx);
    lg[j] = e;
    sum += e;
  }
#pragma unroll
  for (int off = 32; off > 0; off >>= 1) sum += __shfl_xor(sum, off, 64);
  if ((t & 63) == 0) ssum[t >> 6] = sum;
  __syncthreads();
  sum = ssum[0] + ssum[1] + ssum[2] + ssum[3];
  float inv = 1.0f / sum;
#pragma unroll
  for (int j = 0; j < 8; j++) {
    Sb[(size_t)n * NNODES + t + j * 256] = f2bf(lg[j] * inv);
  }
}

// ---------------------------------------------------------------------------
// x (B,N,DIN) f32 -> x_tt (B*DIN, N) bf16 : x_tt[b*64+c][m] = x[b][m][c]
// grid: (N/64, B), 256 threads
// ---------------------------------------------------------------------------
__global__ __launch_bounds__(256) void trans_x(const float* __restrict__ x,
                                               u16* __restrict__ xtt) {
  __shared__ float tile[64][68];
  int b = blockIdx.y;
  int m0 = blockIdx.x * 64;
  int t = threadIdx.x;
  int r = t >> 2, cs = (t & 3) * 16;
  const float* xp = x + ((size_t)b * NNODES + m0 + r) * DIN + cs;
  float4 v0 = ((const float4*)xp)[0];
  float4 v1 = ((const float4*)xp)[1];
  float4 v2 = ((const float4*)xp)[2];
  float4 v3 = ((const float4*)xp)[3];
  *(float4*)&tile[r][cs]      = v0;
  *(float4*)&tile[r][cs + 4]  = v1;
  *(float4*)&tile[r][cs + 8]  = v2;
  *(float4*)&tile[r][cs + 12] = v3;
  __syncthreads();
  int c = t >> 2, ms = (t & 3) * 16;
  short8 o0, o1;
#pragma unroll
  for (int j = 0; j < 8; j++) o0[j] = (short)f2bf(tile[ms + j][c]);
#pragma unroll
  for (int j = 0; j < 8; j++) o1[j] = (short)f2bf(tile[ms + 8 + j][c]);
  u16* op = xtt + ((size_t)b * 64 + c) * NNODES + m0 + ms;
  *(short8*)op = o0;
  *(short8*)(op + 8) = o1;
}

// ---------------------------------------------------------------------------
// bf16 transpose (R x C) -> (C x R), 64x64 tiles. grid: (C/64, R/64)
// ---------------------------------------------------------------------------
__global__ __launch_bounds__(256) void trans_bf(const u16* __restrict__ in,
                                                u16* __restrict__ out,
                                                int R, int C) {
  __shared__ u16 tile[64][72];
  int r0 = blockIdx.y * 64, c0 = blockIdx.x * 64;
  int t = threadIdx.x;
  int r = t >> 2, cs = (t & 3) * 16;
  const u16* ip = in + (size_t)(r0 + r) * C + c0 + cs;
  *(short8*)&tile[r][cs]     = *(const short8*)ip;
  *(short8*)&tile[r][cs + 8] = *(const short8*)(ip + 8);
  __syncthreads();
  int c = t >> 2, ms = (t & 3) * 16;
  short8 o0, o1;
#pragma unroll
  for (int j = 0; j < 8; j++) o0[j] = (short)tile[ms + j][c];
#pragma unroll
  for (int j = 0; j < 8; j++) o1[j] = (short)tile[ms + 8 + j][c];
  u16* op = out + (size_t)(c0 + c) * R + r0 + ms;
  *(short8*)op = o0;
  *(short8*)(op + 8) = o1;
}

// ---------------------------------------------------------------------------
// peff[d][o*192 + k*64 + i] = pool_eff[d][k][i][o] (fp32, 16x12288)
// pool_eff folds T0/T2: k0 -> p0 - p2 ; k2 -> 2*p2
// one-shot reorder so wgen2's per-e loads are coalesced. grid: 768 x 256
// ---------------------------------------------------------------------------
__global__ __launch_bounds__(256) void peff_k(const float* __restrict__ pool,
                                              float* __restrict__ peff) {
  int idx = blockIdx.x * 256 + threadIdx.x;  // < 16*12288
  int d = idx / 12288;
  int r = idx - d * 12288;
  int o = r / 192;
  int ki = r - o * 192;
  int k = ki >> 6, i = ki & 63;
  float p = pool[(size_t)d * 12288 + k * 4096 + i * 64 + o];
  if (k == 0) p -= pool[(size_t)d * 12288 + 8192 + i * 64 + o];
  if (k == 2) p += p;
  peff[idx] = p;
}

// ---------------------------------------------------------------------------
// W[n][e] = sum_d E[n][d] * peff[d][e]  (bf16 out), e = o*192 + k*64 + i
// coalesced peff loads (consecutive lanes -> consecutive e), E tile in LDS.
// grid: (12288/256, 2048/128), 256 threads
// ---------------------------------------------------------------------------
__global__ __launch_bounds__(256) void wgen2(const float* __restrict__ E,
                                             const float* __restrict__ peff,
                                             u16* __restrict__ W) {
  __shared__ float Es[128][17];
  int t = threadIdx.x;
  int n0 = blockIdx.y * 128;
  for (int idx = t; idx < 128 * EMB; idx += 256)
    Es[idx >> 4][idx & 15] = E[(size_t)n0 * EMB + idx];
  int e = blockIdx.x * 256 + t;
  float pv[16];
#pragma unroll
  for (int d = 0; d < 16; d++) pv[d] = peff[(size_t)d * 12288 + e];
  __syncthreads();
#pragma unroll 4
  for (int nn = 0; nn < 128; nn++) {
    float acc = 0.0f;
#pragma unroll
    for (int d = 0; d < 16; d++) acc = fmaf(Es[nn][d], pv[d], acc);
    W[(size_t)(n0 + nn) * 12288 + e] = f2bf(acc);
  }
}

// ---------------------------------------------------------------------------
// bf16 GEMM, m97 structure: C(MxN) = A(MxK) * Bt(NxK)^T, all row-major bf16.
// 128x128 tile, BK=32, 256 threads (4 waves, 2x2 of 64x64), global_load_lds.
// ---------------------------------------------------------------------------
__global__ __launch_bounds__(256) void gemm_bt(const u16* __restrict__ A,
                                               const u16* __restrict__ Bt,
                                               u16* __restrict__ C,
                                               int M, int Nn, int K) {
  __shared__ u16 As[4096];  // [128][32]
  __shared__ u16 Bs[4096];  // [128][32]
  int t = threadIdx.x, lane = t & 63, wave = t >> 6;
  int m0 = blockIdx.y * 128, n0 = blockIdx.x * 128;
  int c0 = t, c1 = t + 256;
  const u16* ag0 = A + (size_t)(m0 + (c0 >> 2)) * K + (c0 & 3) * 8;
  const u16* ag1 = A + (size_t)(m0 + (c1 >> 2)) * K + (c1 & 3) * 8;
  const u16* bg0 = Bt + (size_t)(n0 + (c0 >> 2)) * K + (c0 & 3) * 8;
  const u16* bg1 = Bt + (size_t)(n0 + (c1 >> 2)) * K + (c1 & 3) * 8;
  u16* lA0 = As + wave * 512;
  u16* lA1 = As + 2048 + wave * 512;
  u16* lB0 = Bs + wave * 512;
  u16* lB1 = Bs + 2048 + wave * 512;

  int wr = wave >> 1, wc = wave & 1;
  int lr = lane & 15, kof = (lane >> 4) * 8;

  floatx4 acc[4][4];
#pragma unroll
  for (int mi = 0; mi < 4; mi++)
#pragma unroll
    for (int ni = 0; ni < 4; ni++) acc[mi][ni] = (floatx4)0.0f;

  for (int kt = 0; kt < K; kt += 32) {
    gload_lds16(ag0 + kt, lA0);
    gload_lds16(ag1 + kt, lA1);
    gload_lds16(bg0 + kt, lB0);
    gload_lds16(bg1 + kt, lB1);
    __syncthreads();  // drains vmcnt(0): staged data visible to all waves
    short8 af[4], bf[4];
#pragma unroll
    for (int mi = 0; mi < 4; mi++)
      af[mi] = *(const short8*)&As[(wr * 64 + mi * 16 + lr) * 32 + kof];
#pragma unroll
    for (int ni = 0; ni < 4; ni++)
      bf[ni] = *(const short8*)&Bs[(wc * 64 + ni * 16 + lr) * 32 + kof];
#pragma unroll
    for (int mi = 0; mi < 4; mi++)
#pragma unroll
      for (int ni = 0; ni < 4; ni++)
        acc[mi][ni] = __builtin_amdgcn_mfma_f32_16x16x32_bf16(af[mi], bf[ni],
                                                              acc[mi][ni], 0, 0, 0);
    __syncthreads();  // protect LDS against next iteration's staging
  }

#pragma unroll
  for (int mi = 0; mi < 4; mi++)
#pragma unroll
    for (int ni = 0; ni < 4; ni++) {
      int row = m0 + wr * 64 + mi * 16 + (lane >> 4) * 4;
      int col = n0 + wc * 64 + ni * 16 + lr;
#pragma unroll
      for (int r = 0; r < 4; r++)
        C[(size_t)(row + r) * Nn + col] = f2bf(acc[mi][ni][r]);
    }
}

// ---------------------------------------------------------------------------
// Final per-node fused GEMM: out[b,n,o] = sum_kk A[b,kk]*Weff[n,kk,o] + bias[n,o]
// A[:,0:64]=bf16(x[:,n,:]), A[:,64:128]=xg1[n], A[:,128:192]=xg2[n]
// one block per node, 256 threads (4 waves, 16 b-rows each)
// ---------------------------------------------------------------------------
__global__ __launch_bounds__(256) void final_k(const float* __restrict__ x,
                                               const float* __restrict__ E,
                                               const float* __restrict__ bpool,
                                               const u16* __restrict__ xg1,
                                               const u16* __restrict__ xg2,
                                               const u16* __restrict__ W,
                                               float* __restrict__ out) {
  __shared__ u16 Xs[3][64][72];   // [k][b][i], +8 pad: 2-way banks only
  __shared__ u16 Ws[64][200];     // [o][k*64+i], +8 pad
  __shared__ float bias_s[64];
  int n = blockIdx.x, t = threadIdx.x;

  {  // stage k=0 slab from fp32 x
    int b = t >> 2, i0 = (t & 3) * 16;
    const float* xp = x + ((size_t)b * NNODES + n) * DIN + i0;
    float4 v0 = ((const float4*)xp)[0];
    float4 v1 = ((const float4*)xp)[1];
    float4 v2 = ((const float4*)xp)[2];
    float4 v3 = ((const float4*)xp)[3];
    u16* d = &Xs[0][b][i0];
    d[0] = f2bf(v0.x); d[1] = f2bf(v0.y); d[2] = f2bf(v0.z); d[3] = f2bf(v0.w);
    d[4] = f2bf(v1.x); d[5] = f2bf(v1.y); d[6] = f2bf(v1.z); d[7] = f2bf(v1.w);
    d[8] = f2bf(v2.x); d[9] = f2bf(v2.y); d[10] = f2bf(v2.z); d[11] = f2bf(v2.w);
    d[12] = f2bf(v3.x); d[13] = f2bf(v3.y); d[14] = f2bf(v3.z); d[15] = f2bf(v3.w);
  }
  for (int idx = t; idx < 512; idx += 256) {  // k=1,2 slabs (rows of xg1/xg2)
    short8 v1 = *(const short8*)(xg1 + (size_t)n * 4096 + idx * 8);
    *(short8*)&Xs[1][idx >> 3][(idx & 7) * 8] = v1;
    short8 v2 = *(const short8*)(xg2 + (size_t)n * 4096 + idx * 8);
    *(short8*)&Xs[2][idx >> 3][(idx & 7) * 8] = v2;
  }
  for (int idx = t; idx < 1536; idx += 256) {  // weights: 24 chunks per o-row
    short8 v = *(const short8*)(W + (size_t)n * 12288 + idx * 8);
    int o = idx / 24, w8 = idx - o * 24;
    *(short8*)&Ws[o][w8 * 8] = v;
  }
  if (t < 64) {
    float acc = 0.0f;
#pragma unroll
    for (int d = 0; d < 16; d++)
      acc = fmaf(E[(size_t)n * EMB + d], bpool[d * 64 + t], acc);
    bias_s[t] = acc;
  }
  __syncthreads();

  int lane = t & 63, wave = t >> 6;
  int lr = lane & 15, lg = lane >> 4;
  int wb = wave * 16;
  floatx4 acc[4];
#pragma unroll
  for (int ot = 0; ot < 4; ot++) acc[ot] = (floatx4)0.0f;

#pragma unroll
  for (int ks = 0; ks < 6; ks++) {
    int kk = ks * 32 + lg * 8;
    short8 a = *(const short8*)&Xs[kk >> 6][wb + lr][kk & 63];
#pragma unroll
    for (int ot = 0; ot < 4; ot++) {
      short8 bb = *(const short8*)&Ws[ot * 16 + lr][kk];
      acc[ot] = __builtin_amdgcn_mfma_f32_16x16x32_bf16(a, bb, acc[ot], 0, 0, 0);
    }
  }
#pragma unroll
  for (int ot = 0; ot < 4; ot++) {
    int o = ot * 16 + lr;
    float bs = bias_s[o];
#pragma unroll
    for (int r = 0; r < 4; r++) {
      int b = wb + lg * 4 + r;
      out[((size_t)b * NNODES + n) * DOUT + o] = acc[ot][r] + bs;
    }
  }
}

// ---------------------------------------------------------------------------
extern "C" void kernel_launch(void* const* d_in, const int* in_sizes, int n_in,
                              void* d_out, int out_size, void* d_ws, size_t ws_size,
                              hipStream_t stream) {
  const float* x     = (const float*)d_in[0];  // (64,2048,64)
  const float* E     = (const float*)d_in[1];  // (2048,16)
  const float* pool  = (const float*)d_in[2];  // (16,3,64,64)
  const float* bpool = (const float*)d_in[3];  // (16,64)
  float* out = (float*)d_out;

  char* ws = (char*)d_ws;
  u16* Sb   = (u16*)(ws);                    // 2048*2048*2  = 8 MiB
  u16* xtt  = (u16*)(ws + 8388608);          // 4096*2048*2  = 16 MiB
  u16* xg1  = (u16*)(ws + 25165824);         // 2048*4096*2
  u16* xg1t = (u16*)(ws + 41943040);         // 4096*2048*2
  u16* xg2  = (u16*)(ws + 58720256);         // 2048*4096*2
  u16* Wall = (u16*)(ws + 75497472);         // 2048*12288*2 = 48 MiB  (end 120 MiB)
  // peff (16x12288 fp32, 768 KB) lives inside the xg2 region: xg2 is written
  // only by gemm2, which runs AFTER wgen2 has consumed peff. No extra ws.
  float* peff = (float*)(ws + 58720256);

  peff_k<<<768, 256, 0, stream>>>(pool, peff);
  adj_softmax<<<NNODES, 256, 0, stream>>>(E, Sb);
  trans_x<<<dim3(NNODES / 64, BATCH), 256, 0, stream>>>(x, xtt);
  wgen2<<<dim3(48, NNODES / 128), 256, 0, stream>>>(E, peff, Wall);
  // xg1[n][b*64+c] = sum_m S[n][m] * x[b][m][c]
  gemm_bt<<<dim3(4096 / 128, NNODES / 128), 256, 0, stream>>>(Sb, xtt, xg1,
                                                              NNODES, 4096, NNODES);
  trans_bf<<<dim3(4096 / 64, NNODES / 64), 256, 0, stream>>>(xg1, xg1t, NNODES, 4096);
  // xg2[n][bc] = sum_m S[n][m] * xg1[m][bc]   (un-scaled; T2 folded into Weff)
  gemm_bt<<<dim3(4096 / 128, NNODES / 128), 256, 0, stream>>>(Sb, xg1t, xg2,
                                                              NNODES, 4096, NNODES);
  final_k<<<NNODES, 256, 0, stream>>>(x, E, bpool, xg1, xg2, Wall, out);
}

// Round 3
// 173.676 us; speedup vs baseline: 1.3927x; 1.1725x over previous
//
#include <hip/hip_runtime.h>
#include <hip/hip_bf16.h>

typedef unsigned short u16;
typedef short short8 __attribute__((ext_vector_type(8)));
typedef float floatx4 __attribute__((ext_vector_type(4)));

#define NNODES 2048
#define BATCH  64
#define DIN    64
#define DOUT   64
#define EMB    16

__device__ __forceinline__ u16 f2bf(float f) {
  union { float f; unsigned u; } v; v.f = f;
  unsigned r = v.u + 0x7fffu + ((v.u >> 16) & 1u);
  return (u16)(r >> 16);
}

__device__ __forceinline__ void gload_lds16(const void* g, void* l) {
  __builtin_amdgcn_global_load_lds(
      (const __attribute__((address_space(1))) void*)g,
      (__attribute__((address_space(3))) void*)l, 16, 0, 0);
}

// ---------------------------------------------------------------------------
// S = softmax(relu(E E^T), axis=1), output bf16 (2048 x 2048)
// ---------------------------------------------------------------------------
__global__ __launch_bounds__(256) void adj_softmax(const float* __restrict__ E,
                                                   u16* __restrict__ Sb) {
  int n = blockIdx.x, t = threadIdx.x;
  const float4* ep = (const float4*)(E + (size_t)n * EMB);
  float4 e0 = ep[0], e1 = ep[1], e2 = ep[2], e3 = ep[3];

  float lg[8];
  float mx = 0.0f;  // relu => all logits >= 0
#pragma unroll
  for (int j = 0; j < 8; j++) {
    int m = t + j * 256;
    const float4* mp = (const float4*)(E + (size_t)m * EMB);
    float4 a = mp[0], b = mp[1], c = mp[2], d = mp[3];
    float dot = e0.x * a.x + e0.y * a.y + e0.z * a.z + e0.w * a.w
              + e1.x * b.x + e1.y * b.y + e1.z * b.z + e1.w * b.w
              + e2.x * c.x + e2.y * c.y + e2.z * c.z + e2.w * c.w
              + e3.x * d.x + e3.y * d.y + e3.z * d.z + e3.w * d.w;
    dot = fmaxf(dot, 0.0f);
    lg[j] = dot;
    mx = fmaxf(mx, dot);
  }
  __shared__ float smax[4], ssum[4];
#pragma unroll
  for (int off = 32; off > 0; off >>= 1) mx = fmaxf(mx, __shfl_xor(mx, off, 64));
  if ((t & 63) == 0) smax[t >> 6] = mx;
  __syncthreads();
  mx = fmaxf(fmaxf(smax[0], smax[1]), fmaxf(smax[2], smax[3]));

  float sum = 0.0f;
#pragma unroll
  for (int j = 0; j < 8; j++) {
    float e = __expf(lg[j] - mx);
    lg[j] = e;
    sum += e;
  }
#pragma unroll
  for (int off = 32; off > 0; off >>= 1) sum += __shfl_xor(sum, off, 64);
  if ((t & 63) == 0) ssum[t >> 6] = sum;
  __syncthreads();
  sum = ssum[0] + ssum[1] + ssum[2] + ssum[3];
  float inv = 1.0f / sum;
#pragma unroll
  for (int j = 0; j < 8; j++) {
    Sb[(size_t)n * NNODES + t + j * 256] = f2bf(lg[j] * inv);
  }
}

// ---------------------------------------------------------------------------
// x (B,N,DIN) f32 -> x_tt (B*DIN, N) bf16 : x_tt[b*64+c][m] = x[b][m][c]
// ---------------------------------------------------------------------------
__global__ __launch_bounds__(256) void trans_x(const float* __restrict__ x,
                                               u16* __restrict__ xtt) {
  __shared__ float tile[64][68];
  int b = blockIdx.y;
  int m0 = blockIdx.x * 64;
  int t = threadIdx.x;
  int r = t >> 2, cs = (t & 3) * 16;
  const float* xp = x + ((size_t)b * NNODES + m0 + r) * DIN + cs;
  float4 v0 = ((const float4*)xp)[0];
  float4 v1 = ((const float4*)xp)[1];
  float4 v2 = ((const float4*)xp)[2];
  float4 v3 = ((const float4*)xp)[3];
  *(float4*)&tile[r][cs]      = v0;
  *(float4*)&tile[r][cs + 4]  = v1;
  *(float4*)&tile[r][cs + 8]  = v2;
  *(float4*)&tile[r][cs + 12] = v3;
  __syncthreads();
  int c = t >> 2, ms = (t & 3) * 16;
  short8 o0, o1;
#pragma unroll
  for (int j = 0; j < 8; j++) o0[j] = (short)f2bf(tile[ms + j][c]);
#pragma unroll
  for (int j = 0; j < 8; j++) o1[j] = (short)f2bf(tile[ms + 8 + j][c]);
  u16* op = xtt + ((size_t)b * 64 + c) * NNODES + m0 + ms;
  *(short8*)op = o0;
  *(short8*)(op + 8) = o1;
}

// ---------------------------------------------------------------------------
// bf16 transpose (R x C) -> (C x R), 64x64 tiles. grid: (C/64, R/64)
// ---------------------------------------------------------------------------
__global__ __launch_bounds__(256) void trans_bf(const u16* __restrict__ in,
                                                u16* __restrict__ out,
                                                int R, int C) {
  __shared__ u16 tile[64][72];
  int r0 = blockIdx.y * 64, c0 = blockIdx.x * 64;
  int t = threadIdx.x;
  int r = t >> 2, cs = (t & 3) * 16;
  const u16* ip = in + (size_t)(r0 + r) * C + c0 + cs;
  *(short8*)&tile[r][cs]     = *(const short8*)ip;
  *(short8*)&tile[r][cs + 8] = *(const short8*)(ip + 8);
  __syncthreads();
  int c = t >> 2, ms = (t & 3) * 16;
  short8 o0, o1;
#pragma unroll
  for (int j = 0; j < 8; j++) o0[j] = (short)tile[ms + j][c];
#pragma unroll
  for (int j = 0; j < 8; j++) o1[j] = (short)tile[ms + 8 + j][c];
  u16* op = out + (size_t)(c0 + c) * R + r0 + ms;
  *(short8*)op = o0;
  *(short8*)(op + 8) = o1;
}

// ---------------------------------------------------------------------------
// peff[d][o*192 + k*64 + i] = pool_eff[d][k][i][o] (fp32, 16x12288)
// pool_eff folds T0/T2: k0 -> p0 - p2 ; k2 -> 2*p2
// ---------------------------------------------------------------------------
__global__ __launch_bounds__(256) void peff_k(const float* __restrict__ pool,
                                              float* __restrict__ peff) {
  int idx = blockIdx.x * 256 + threadIdx.x;  // < 16*12288
  int d = idx / 12288;
  int r = idx - d * 12288;
  int o = r / 192;
  int ki = r - o * 192;
  int k = ki >> 6, i = ki & 63;
  float p = pool[(size_t)d * 12288 + k * 4096 + i * 64 + o];
  if (k == 0) p -= pool[(size_t)d * 12288 + 8192 + i * 64 + o];
  if (k == 2) p += p;
  peff[idx] = p;
}

// ---------------------------------------------------------------------------
// W[n][e] = sum_d E[n][d] * peff[d][e]  (bf16 out), e = o*192 + k*64 + i
// ---------------------------------------------------------------------------
__global__ __launch_bounds__(256) void wgen2(const float* __restrict__ E,
                                             const float* __restrict__ peff,
                                             u16* __restrict__ W) {
  __shared__ float Es[128][17];
  int t = threadIdx.x;
  int n0 = blockIdx.y * 128;
  for (int idx = t; idx < 128 * EMB; idx += 256)
    Es[idx >> 4][idx & 15] = E[(size_t)n0 * EMB + idx];
  int e = blockIdx.x * 256 + t;
  float pv[16];
#pragma unroll
  for (int d = 0; d < 16; d++) pv[d] = peff[(size_t)d * 12288 + e];
  __syncthreads();
#pragma unroll 4
  for (int nn = 0; nn < 128; nn++) {
    float acc = 0.0f;
#pragma unroll
    for (int d = 0; d < 16; d++) acc = fmaf(Es[nn][d], pv[d], acc);
    W[(size_t)(n0 + nn) * 12288 + e] = f2bf(acc);
  }
}

// ---------------------------------------------------------------------------
// Deep-pipelined bf16 GEMM: C(2048 x 4096) = A(2048 x 2048) * Bt(4096 x 2048)^T
// BM=256, BN=128, BK=64. 512 threads = 8 waves (4M x 2N, 64x64 each).
// 3 LDS buffers, stage tile t+2 each iter, counted vmcnt(6) (never 0 in loop),
// raw s_barrier (no implicit drain). XOR swizzle slot^(row&7) applied on the
// GLOBAL source addr (linear global_load_lds dest) and on the ds_read addr
// (rule #21: same involution both sides).
// ---------------------------------------------------------------------------
#define GK 2048      // K
#define GN 4096      // output cols
#define NT 32        // K / 64
#define BUFU 24576   // u16 per buffer: A 256*64=16384 + B 128*64=8192

__global__ __launch_bounds__(512) void gemm_dp(const u16* __restrict__ A,
                                               const u16* __restrict__ Bt,
                                               u16* __restrict__ C) {
  __shared__ u16 smem[3 * BUFU];  // 147456 B
  int t = threadIdx.x, lane = t & 63, wave = t >> 6;

  // XCD-chunked bijective swizzle: grid = 32 x 8 = 256 (nwg % 8 == 0)
  int lin = blockIdx.y * gridDim.x + blockIdx.x;
  int nwg = gridDim.x * gridDim.y;
  int sw = (lin & 7) * (nwg >> 3) + (lin >> 3);
  int bx = sw & 31, by = sw >> 5;            // gridDim.x == 32
  int m0 = by * 256, n0 = bx * 128;

  // ---- staging address precompute: A 4 chunks, B 2 chunks per thread ----
  const u16* pg[6];
  int lof[6];
#pragma unroll
  for (int j = 0; j < 4; j++) {
    int c = t + 512 * j;
    int row = c >> 3;
    int gs = (c & 7) ^ (row & 7);
    pg[j] = A + (size_t)(m0 + row) * GK + gs * 8;
    lof[j] = c * 8;
  }
#pragma unroll
  for (int j = 0; j < 2; j++) {
    int c = t + 512 * j;
    int row = c >> 3;
    int gs = (c & 7) ^ (row & 7);
    pg[4 + j] = Bt + (size_t)(n0 + row) * GK + gs * 8;
    lof[4 + j] = 16384 + c * 8;
  }

  auto stage = [&](int b, int kt) {
#pragma unroll
    for (int j = 0; j < 6; j++)
      gload_lds16(pg[j] + kt, &smem[b * BUFU + lof[j]]);
  };

  // ---- per-wave fragment geometry ----
  int wr = wave >> 1, wc = wave & 1;   // 4M x 2N
  int lr = lane & 15, lg = lane >> 4;  // lg in 0..3

  floatx4 acc[4][4];
#pragma unroll
  for (int mi = 0; mi < 4; mi++)
#pragma unroll
    for (int ni = 0; ni < 4; ni++) acc[mi][ni] = (floatx4)0.0f;

  // precompute swizzled LDS u16-offsets for the 16 frag reads (per ksub s)
  int aoff[2][4], boff[2][4];
#pragma unroll
  for (int s = 0; s < 2; s++) {
#pragma unroll
    for (int mi = 0; mi < 4; mi++) {
      int row = wr * 64 + mi * 16 + lr;
      int slot = s * 4 + lg;
      aoff[s][mi] = row * 64 + (slot ^ (row & 7)) * 8;
    }
#pragma unroll
    for (int ni = 0; ni < 4; ni++) {
      int row = wc * 64 + ni * 16 + lr;
      int slot = s * 4 + lg;
      boff[s][ni] = 16384 + row * 64 + (slot ^ (row & 7)) * 8;
    }
  }

  auto compute = [&](int b) {
    const u16* base = &smem[b * BUFU];
    short8 af[2][4], bf[2][4];
#pragma unroll
    for (int s = 0; s < 2; s++) {
#pragma unroll
      for (int mi = 0; mi < 4; mi++) af[s][mi] = *(const short8*)(base + aoff[s][mi]);
#pragma unroll
      for (int ni = 0; ni < 4; ni++) bf[s][ni] = *(const short8*)(base + boff[s][ni]);
    }
#pragma unroll
    for (int s = 0; s < 2; s++)
#pragma unroll
      for (int mi = 0; mi < 4; mi++)
#pragma unroll
        for (int ni = 0; ni < 4; ni++)
          acc[mi][ni] = __builtin_amdgcn_mfma_f32_16x16x32_bf16(af[s][mi], bf[s][ni],
                                                                acc[mi][ni], 0, 0, 0);
  };

  // ---- prologue: stage tiles 0,1 ----
  stage(0, 0);
  stage(1, 64);

  // ---- main loop: tiles 0 .. NT-3 ----
  for (int tt = 0; tt < NT - 2; ++tt) {
    asm volatile("s_waitcnt vmcnt(6)" ::: "memory");  // own stage(tt) landed
    __builtin_amdgcn_s_barrier();                     // everyone's stage(tt) landed;
                                                      // all reads of buf (tt-1)%3 done
    stage((tt + 2) % 3, (tt + 2) * 64);               // 6 loads into the freed buffer
    compute(tt % 3);
  }
  // ---- tail: tile NT-2 (stage NT-1 still in flight), then NT-1 ----
  asm volatile("s_waitcnt vmcnt(6)" ::: "memory");
  __builtin_amdgcn_s_barrier();
  compute((NT - 2) % 3);
  asm volatile("s_waitcnt vmcnt(0)" ::: "memory");
  __builtin_amdgcn_s_barrier();
  compute((NT - 1) % 3);

  // ---- epilogue ----
#pragma unroll
  for (int mi = 0; mi < 4; mi++)
#pragma unroll
    for (int ni = 0; ni < 4; ni++) {
      int row = m0 + wr * 64 + mi * 16 + lg * 4;
      int col = n0 + wc * 64 + ni * 16 + lr;
#pragma unroll
      for (int r = 0; r < 4; r++)
        C[(size_t)(row + r) * GN + col] = f2bf(acc[mi][ni][r]);
    }
}

// ---------------------------------------------------------------------------
// Final per-node fused GEMM: out[b,n,o] = sum_kk A[b,kk]*Weff[n,kk,o] + bias[n,o]
// ---------------------------------------------------------------------------
__global__ __launch_bounds__(256) void final_k(const float* __restrict__ x,
                                               const float* __restrict__ E,
                                               const float* __restrict__ bpool,
                                               const u16* __restrict__ xg1,
                                               const u16* __restrict__ xg2,
                                               const u16* __restrict__ W,
                                               float* __restrict__ out) {
  __shared__ u16 Xs[3][64][72];   // [k][b][i], +8 pad: 2-way banks only
  __shared__ u16 Ws[64][200];     // [o][k*64+i], +8 pad
  __shared__ float bias_s[64];
  int n = blockIdx.x, t = threadIdx.x;

  {  // stage k=0 slab from fp32 x
    int b = t >> 2, i0 = (t & 3) * 16;
    const float* xp = x + ((size_t)b * NNODES + n) * DIN + i0;
    float4 v0 = ((const float4*)xp)[0];
    float4 v1 = ((const float4*)xp)[1];
    float4 v2 = ((const float4*)xp)[2];
    float4 v3 = ((const float4*)xp)[3];
    u16* d = &Xs[0][b][i0];
    d[0] = f2bf(v0.x); d[1] = f2bf(v0.y); d[2] = f2bf(v0.z); d[3] = f2bf(v0.w);
    d[4] = f2bf(v1.x); d[5] = f2bf(v1.y); d[6] = f2bf(v1.z); d[7] = f2bf(v1.w);
    d[8] = f2bf(v2.x); d[9] = f2bf(v2.y); d[10] = f2bf(v2.z); d[11] = f2bf(v2.w);
    d[12] = f2bf(v3.x); d[13] = f2bf(v3.y); d[14] = f2bf(v3.z); d[15] = f2bf(v3.w);
  }
  for (int idx = t; idx < 512; idx += 256) {  // k=1,2 slabs (rows of xg1/xg2)
    short8 v1 = *(const short8*)(xg1 + (size_t)n * 4096 + idx * 8);
    *(short8*)&Xs[1][idx >> 3][(idx & 7) * 8] = v1;
    short8 v2 = *(const short8*)(xg2 + (size_t)n * 4096 + idx * 8);
    *(short8*)&Xs[2][idx >> 3][(idx & 7) * 8] = v2;
  }
  for (int idx = t; idx < 1536; idx += 256) {  // weights: 24 chunks per o-row
    short8 v = *(const short8*)(W + (size_t)n * 12288 + idx * 8);
    int o = idx / 24, w8 = idx - o * 24;
    *(short8*)&Ws[o][w8 * 8] = v;
  }
  if (t < 64) {
    float acc = 0.0f;
#pragma unroll
    for (int d = 0; d < 16; d++)
      acc = fmaf(E[(size_t)n * EMB + d], bpool[d * 64 + t], acc);
    bias_s[t] = acc;
  }
  __syncthreads();

  int lane = t & 63, wave = t >> 6;
  int lr = lane & 15, lg = lane >> 4;
  int wb = wave * 16;
  floatx4 acc[4];
#pragma unroll
  for (int ot = 0; ot < 4; ot++) acc[ot] = (floatx4)0.0f;

#pragma unroll
  for (int ks = 0; ks < 6; ks++) {
    int kk = ks * 32 + lg * 8;
    short8 a = *(const short8*)&Xs[kk >> 6][wb + lr][kk & 63];
#pragma unroll
    for (int ot = 0; ot < 4; ot++) {
      short8 bb = *(const short8*)&Ws[ot * 16 + lr][kk];
      acc[ot] = __builtin_amdgcn_mfma_f32_16x16x32_bf16(a, bb, acc[ot], 0, 0, 0);
    }
  }
#pragma unroll
  for (int ot = 0; ot < 4; ot++) {
    int o = ot * 16 + lr;
    float bs = bias_s[o];
#pragma unroll
    for (int r = 0; r < 4; r++) {
      int b = wb + lg * 4 + r;
      out[((size_t)b * NNODES + n) * DOUT + o] = acc[ot][r] + bs;
    }
  }
}

// ---------------------------------------------------------------------------
extern "C" void kernel_launch(void* const* d_in, const int* in_sizes, int n_in,
                              void* d_out, int out_size, void* d_ws, size_t ws_size,
                              hipStream_t stream) {
  const float* x     = (const float*)d_in[0];  // (64,2048,64)
  const float* E     = (const float*)d_in[1];  // (2048,16)
  const float* pool  = (const float*)d_in[2];  // (16,3,64,64)
  const float* bpool = (const float*)d_in[3];  // (16,64)
  float* out = (float*)d_out;

  char* ws = (char*)d_ws;
  u16* Sb   = (u16*)(ws);                    // 2048*2048*2  = 8 MiB
  u16* xtt  = (u16*)(ws + 8388608);          // 4096*2048*2  = 16 MiB
  u16* xg1  = (u16*)(ws + 25165824);         // 2048*4096*2
  u16* xg1t = (u16*)(ws + 41943040);         // 4096*2048*2
  u16* xg2  = (u16*)(ws + 58720256);         // 2048*4096*2
  u16* Wall = (u16*)(ws + 75497472);         // 2048*12288*2 = 48 MiB  (end 120 MiB)
  // peff (16x12288 fp32, 768 KB) lives inside the xg2 region: xg2 is written
  // only by gemm2, which runs AFTER wgen2 has consumed peff. No extra ws.
  float* peff = (float*)(ws + 58720256);

  peff_k<<<768, 256, 0, stream>>>(pool, peff);
  adj_softmax<<<NNODES, 256, 0, stream>>>(E, Sb);
  trans_x<<<dim3(NNODES / 64, BATCH), 256, 0, stream>>>(x, xtt);
  wgen2<<<dim3(48, NNODES / 128), 256, 0, stream>>>(E, peff, Wall);
  // xg1[n][b*64+c] = sum_m S[n][m] * x[b][m][c]
  gemm_dp<<<dim3(32, 8), 512, 0, stream>>>(Sb, xtt, xg1);
  trans_bf<<<dim3(4096 / 64, NNODES / 64), 256, 0, stream>>>(xg1, xg1t, NNODES, 4096);
  // xg2[n][bc] = sum_m S[n][m] * xg1[m][bc]   (un-scaled; T2 folded into Weff)
  gemm_dp<<<dim3(32, 8), 512, 0, stream>>>(Sb, xg1t, xg2);
  final_k<<<NNODES, 256, 0, stream>>>(x, E, bpool, xg1, xg2, Wall, out);
}

// Round 4
// 170.548 us; speedup vs baseline: 1.4182x; 1.0183x over previous
//
#include <hip/hip_runtime.h>
#include <hip/hip_bf16.h>

typedef unsigned short u16;
typedef short short8 __attribute__((ext_vector_type(8)));
typedef float floatx4 __attribute__((ext_vector_type(4)));

#define NNODES 2048
#define BATCH  64
#define DIN    64
#define DOUT   64
#define EMB    16

__device__ __forceinline__ u16 f2bf(float f) {
  union { float f; unsigned u; } v; v.f = f;
  unsigned r = v.u + 0x7fffu + ((v.u >> 16) & 1u);
  return (u16)(r >> 16);
}

__device__ __forceinline__ void gload_lds16(const void* g, void* l) {
  __builtin_amdgcn_global_load_lds(
      (const __attribute__((address_space(1))) void*)g,
      (__attribute__((address_space(3))) void*)l, 16, 0, 0);
}

// ---------------------------------------------------------------------------
// S = softmax(relu(E E^T), axis=1), output bf16 (2048 x 2048)
// ---------------------------------------------------------------------------
__global__ __launch_bounds__(256) void adj_softmax(const float* __restrict__ E,
                                                   u16* __restrict__ Sb) {
  int n = blockIdx.x, t = threadIdx.x;
  const float4* ep = (const float4*)(E + (size_t)n * EMB);
  float4 e0 = ep[0], e1 = ep[1], e2 = ep[2], e3 = ep[3];

  float lg[8];
  float mx = 0.0f;  // relu => all logits >= 0
#pragma unroll
  for (int j = 0; j < 8; j++) {
    int m = t + j * 256;
    const float4* mp = (const float4*)(E + (size_t)m * EMB);
    float4 a = mp[0], b = mp[1], c = mp[2], d = mp[3];
    float dot = e0.x * a.x + e0.y * a.y + e0.z * a.z + e0.w * a.w
              + e1.x * b.x + e1.y * b.y + e1.z * b.z + e1.w * b.w
              + e2.x * c.x + e2.y * c.y + e2.z * c.z + e2.w * c.w
              + e3.x * d.x + e3.y * d.y + e3.z * d.z + e3.w * d.w;
    dot = fmaxf(dot, 0.0f);
    lg[j] = dot;
    mx = fmaxf(mx, dot);
  }
  __shared__ float smax[4], ssum[4];
#pragma unroll
  for (int off = 32; off > 0; off >>= 1) mx = fmaxf(mx, __shfl_xor(mx, off, 64));
  if ((t & 63) == 0) smax[t >> 6] = mx;
  __syncthreads();
  mx = fmaxf(fmaxf(smax[0], smax[1]), fmaxf(smax[2], smax[3]));

  float sum = 0.0f;
#pragma unroll
  for (int j = 0; j < 8; j++) {
    float e = __expf(lg[j] - mx);
    lg[j] = e;
    sum += e;
  }
#pragma unroll
  for (int off = 32; off > 0; off >>= 1) sum += __shfl_xor(sum, off, 64);
  if ((t & 63) == 0) ssum[t >> 6] = sum;
  __syncthreads();
  sum = ssum[0] + ssum[1] + ssum[2] + ssum[3];
  float inv = 1.0f / sum;
#pragma unroll
  for (int j = 0; j < 8; j++) {
    Sb[(size_t)n * NNODES + t + j * 256] = f2bf(lg[j] * inv);
  }
}

// ---------------------------------------------------------------------------
// x (B,N,DIN) f32 -> x_tt (B*DIN, N) bf16 : x_tt[b*64+c][m] = x[b][m][c]
// ---------------------------------------------------------------------------
__global__ __launch_bounds__(256) void trans_x(const float* __restrict__ x,
                                               u16* __restrict__ xtt) {
  __shared__ float tile[64][68];
  int b = blockIdx.y;
  int m0 = blockIdx.x * 64;
  int t = threadIdx.x;
  int r = t >> 2, cs = (t & 3) * 16;
  const float* xp = x + ((size_t)b * NNODES + m0 + r) * DIN + cs;
  float4 v0 = ((const float4*)xp)[0];
  float4 v1 = ((const float4*)xp)[1];
  float4 v2 = ((const float4*)xp)[2];
  float4 v3 = ((const float4*)xp)[3];
  *(float4*)&tile[r][cs]      = v0;
  *(float4*)&tile[r][cs + 4]  = v1;
  *(float4*)&tile[r][cs + 8]  = v2;
  *(float4*)&tile[r][cs + 12] = v3;
  __syncthreads();
  int c = t >> 2, ms = (t & 3) * 16;
  short8 o0, o1;
#pragma unroll
  for (int j = 0; j < 8; j++) o0[j] = (short)f2bf(tile[ms + j][c]);
#pragma unroll
  for (int j = 0; j < 8; j++) o1[j] = (short)f2bf(tile[ms + 8 + j][c]);
  u16* op = xtt + ((size_t)b * 64 + c) * NNODES + m0 + ms;
  *(short8*)op = o0;
  *(short8*)(op + 8) = o1;
}

// ---------------------------------------------------------------------------
// peff[d][o*192 + k*64 + i] = pool_eff[d][k][i][o] (fp32, 16x12288)
// pool_eff folds T0/T2: k0 -> p0 - p2 ; k2 -> 2*p2
// ---------------------------------------------------------------------------
__global__ __launch_bounds__(256) void peff_k(const float* __restrict__ pool,
                                              float* __restrict__ peff) {
  int idx = blockIdx.x * 256 + threadIdx.x;  // < 16*12288
  int d = idx / 12288;
  int r = idx - d * 12288;
  int o = r / 192;
  int ki = r - o * 192;
  int k = ki >> 6, i = ki & 63;
  float p = pool[(size_t)d * 12288 + k * 4096 + i * 64 + o];
  if (k == 0) p -= pool[(size_t)d * 12288 + 8192 + i * 64 + o];
  if (k == 2) p += p;
  peff[idx] = p;
}

// ---------------------------------------------------------------------------
// W[n][e] = sum_d E[n][d] * peff[d][e]  (bf16 out), e = o*192 + k*64 + i
// ---------------------------------------------------------------------------
__global__ __launch_bounds__(256) void wgen2(const float* __restrict__ E,
                                             const float* __restrict__ peff,
                                             u16* __restrict__ W) {
  __shared__ float Es[128][17];
  int t = threadIdx.x;
  int n0 = blockIdx.y * 128;
  for (int idx = t; idx < 128 * EMB; idx += 256)
    Es[idx >> 4][idx & 15] = E[(size_t)n0 * EMB + idx];
  int e = blockIdx.x * 256 + t;
  float pv[16];
#pragma unroll
  for (int d = 0; d < 16; d++) pv[d] = peff[(size_t)d * 12288 + e];
  __syncthreads();
#pragma unroll 4
  for (int nn = 0; nn < 128; nn++) {
    float acc = 0.0f;
#pragma unroll
    for (int d = 0; d < 16; d++) acc = fmaf(Es[nn][d], pv[d], acc);
    W[(size_t)(n0 + nn) * 12288 + e] = f2bf(acc);
  }
}

// ---------------------------------------------------------------------------
// Deep-pipelined bf16 GEMM: C(2048 x 4096) = A(2048 x 2048) * Bt(4096 x 2048)^T
// BM=256, BN=128, BK=64. 512 threads = 8 waves (4M x 2N, 64x64 each).
// 3 LDS buffers, counted vmcnt(6) (never 0 in the loop). Each K-tile is
// TWO phases: {8 ds_read frags (k-substep) | 3 prefetch gloads | setprio MFMA}
// separated by a scheduling s_barrier (T3 minimum + T5).
// XOR swizzle slot^(row&7) on both global source and ds_read addr (rule #21).
// If Ct != nullptr, also writes C^T via per-wave LDS transpose (kills the
// separate transpose kernel).
// ---------------------------------------------------------------------------
#define GK 2048      // K
#define GN 4096      // output cols
#define NT 32        // K / 64
#define BUFU 24576   // u16 per buffer: A 256*64=16384 + B 128*64=8192

__global__ __launch_bounds__(512) void gemm_dp(const u16* __restrict__ A,
                                               const u16* __restrict__ Bt,
                                               u16* __restrict__ C,
                                               u16* __restrict__ Ct) {
  __shared__ u16 smem[3 * BUFU];  // 147456 B
  int t = threadIdx.x, lane = t & 63, wave = t >> 6;

  // XCD-chunked bijective swizzle: grid = 32 x 8 = 256 (nwg % 8 == 0)
  int lin = blockIdx.y * gridDim.x + blockIdx.x;
  int nwg = gridDim.x * gridDim.y;
  int sw = (lin & 7) * (nwg >> 3) + (lin >> 3);
  int bx = sw & 31, by = sw >> 5;            // gridDim.x == 32
  int m0 = by * 256, n0 = bx * 128;

  // ---- staging address precompute: A 4 chunks, B 2 chunks per thread ----
  const u16* pg[6];
  int lof[6];
#pragma unroll
  for (int j = 0; j < 4; j++) {
    int c = t + 512 * j;
    int row = c >> 3;
    int gs = (c & 7) ^ (row & 7);
    pg[j] = A + (size_t)(m0 + row) * GK + gs * 8;
    lof[j] = c * 8;
  }
#pragma unroll
  for (int j = 0; j < 2; j++) {
    int c = t + 512 * j;
    int row = c >> 3;
    int gs = (c & 7) ^ (row & 7);
    pg[4 + j] = Bt + (size_t)(n0 + row) * GK + gs * 8;
    lof[4 + j] = 16384 + c * 8;
  }

  // ---- per-wave fragment geometry ----
  int wr = wave >> 1, wc = wave & 1;   // 4M x 2N
  int lr = lane & 15, lg = lane >> 4;  // lg in 0..3

  floatx4 acc[4][4];
#pragma unroll
  for (int mi = 0; mi < 4; mi++)
#pragma unroll
    for (int ni = 0; ni < 4; ni++) acc[mi][ni] = (floatx4)0.0f;

  // precompute swizzled LDS u16-offsets for the frag reads (per ksub s)
  int aoff[2][4], boff[2][4];
#pragma unroll
  for (int s = 0; s < 2; s++) {
#pragma unroll
    for (int mi = 0; mi < 4; mi++) {
      int row = wr * 64 + mi * 16 + lr;
      int slot = s * 4 + lg;
      aoff[s][mi] = row * 64 + (slot ^ (row & 7)) * 8;
    }
#pragma unroll
    for (int ni = 0; ni < 4; ni++) {
      int row = wc * 64 + ni * 16 + lr;
      int slot = s * 4 + lg;
      boff[s][ni] = 16384 + row * 64 + (slot ^ (row & 7)) * 8;
    }
  }

  // one phase: read k-substep s frags, issue 3 prefetch loads, MFMA cluster
  auto phase = [&](int bufc, int s, int bufs, int kt, int jlo, bool do_stage) {
    const u16* base = &smem[bufc * BUFU];
    short8 af[4], bf[4];
#pragma unroll
    for (int mi = 0; mi < 4; mi++) af[mi] = *(const short8*)(base + aoff[s][mi]);
#pragma unroll
    for (int ni = 0; ni < 4; ni++) bf[ni] = *(const short8*)(base + boff[s][ni]);
    if (do_stage) {
#pragma unroll
      for (int j = 0; j < 3; j++)
        gload_lds16(pg[jlo + j] + kt, &smem[bufs * BUFU + lof[jlo + j]]);
    }
    __builtin_amdgcn_s_setprio(1);
#pragma unroll
    for (int mi = 0; mi < 4; mi++)
#pragma unroll
      for (int ni = 0; ni < 4; ni++)
        acc[mi][ni] = __builtin_amdgcn_mfma_f32_16x16x32_bf16(af[mi], bf[ni],
                                                              acc[mi][ni], 0, 0, 0);
    __builtin_amdgcn_s_setprio(0);
  };

  // ---- prologue: stage tiles 0,1 ----
#pragma unroll
  for (int j = 0; j < 6; j++) gload_lds16(pg[j], &smem[lof[j]]);
#pragma unroll
  for (int j = 0; j < 6; j++) gload_lds16(pg[j] + 64, &smem[BUFU + lof[j]]);

  // ---- main loop: tiles 0 .. NT-3 ----
  for (int tt = 0; tt < NT - 2; ++tt) {
    int bufc = tt % 3, bufs = (tt + 2) % 3;
    asm volatile("s_waitcnt vmcnt(6)" ::: "memory");  // own stage(tt) landed
    __builtin_amdgcn_s_barrier();                     // all stage(tt) landed;
                                                      // all reads of bufs done
    phase(bufc, 0, bufs, (tt + 2) * 64, 0, true);
    __builtin_amdgcn_s_barrier();                     // scheduling: phase split
    phase(bufc, 1, bufs, (tt + 2) * 64, 3, true);
  }
  // ---- tail: tile NT-2 (stage NT-1 still in flight), then NT-1 ----
  asm volatile("s_waitcnt vmcnt(6)" ::: "memory");
  __builtin_amdgcn_s_barrier();
  phase((NT - 2) % 3, 0, 0, 0, 0, false);
  __builtin_amdgcn_s_barrier();
  phase((NT - 2) % 3, 1, 0, 0, 0, false);
  asm volatile("s_waitcnt vmcnt(0)" ::: "memory");
  __builtin_amdgcn_s_barrier();
  phase((NT - 1) % 3, 0, 0, 0, 0, false);
  __builtin_amdgcn_s_barrier();
  phase((NT - 1) % 3, 1, 0, 0, 0, false);

  // ---- epilogue: row-major C ----
#pragma unroll
  for (int mi = 0; mi < 4; mi++)
#pragma unroll
    for (int ni = 0; ni < 4; ni++) {
      int row = m0 + wr * 64 + mi * 16 + lg * 4;
      int col = n0 + wc * 64 + ni * 16 + lr;
#pragma unroll
      for (int r = 0; r < 4; r++)
        C[(size_t)(row + r) * GN + col] = f2bf(acc[mi][ni][r]);
    }

  // ---- optional transposed epilogue: Ct[col][row] (per-wave LDS transpose) --
  if (Ct) {
    __syncthreads();  // all waves done reading smem buffers
    u16* scr = smem + wave * 64 * 72;  // 8 waves * 4608 u16 = 36864 <= 73728
    // write acc transposed: scr[ncol][mrow]
#pragma unroll
    for (int mi = 0; mi < 4; mi++)
#pragma unroll
      for (int ni = 0; ni < 4; ni++) {
        int ncol = ni * 16 + lr;
#pragma unroll
        for (int r = 0; r < 4; r++)
          scr[ncol * 72 + mi * 16 + lg * 4 + r] = f2bf(acc[mi][ni][r]);
      }
    // lane c reads its row of scr contiguously, stores 128B to Ct row
    int c = lane;
    u16* op = Ct + (size_t)(n0 + wc * 64 + c) * GK + m0 + wr * 64;
    // compiler inserts lgkmcnt for own-wave ds ordering; per-wave scratch only
#pragma unroll
    for (int jj = 0; jj < 8; jj++) {
      short8 v = *(const short8*)&scr[c * 72 + jj * 8];
      *(short8*)(op + jj * 8) = v;
    }
  }
}

// ---------------------------------------------------------------------------
// Final per-node fused GEMM: out[b,n,o] = sum_kk A[b,kk]*Weff[n,kk,o] + bias[n,o]
// ---------------------------------------------------------------------------
__global__ __launch_bounds__(256) void final_k(const float* __restrict__ x,
                                               const float* __restrict__ E,
                                               const float* __restrict__ bpool,
                                               const u16* __restrict__ xg1,
                                               const u16* __restrict__ xg2,
                                               const u16* __restrict__ W,
                                               float* __restrict__ out) {
  __shared__ u16 Xs[3][64][72];   // [k][b][i], +8 pad: 2-way banks only
  __shared__ u16 Ws[64][200];     // [o][k*64+i], +8 pad
  __shared__ float bias_s[64];
  int n = blockIdx.x, t = threadIdx.x;

  {  // stage k=0 slab from fp32 x
    int b = t >> 2, i0 = (t & 3) * 16;
    const float* xp = x + ((size_t)b * NNODES + n) * DIN + i0;
    float4 v0 = ((const float4*)xp)[0];
    float4 v1 = ((const float4*)xp)[1];
    float4 v2 = ((const float4*)xp)[2];
    float4 v3 = ((const float4*)xp)[3];
    u16* d = &Xs[0][b][i0];
    d[0] = f2bf(v0.x); d[1] = f2bf(v0.y); d[2] = f2bf(v0.z); d[3] = f2bf(v0.w);
    d[4] = f2bf(v1.x); d[5] = f2bf(v1.y); d[6] = f2bf(v1.z); d[7] = f2bf(v1.w);
    d[8] = f2bf(v2.x); d[9] = f2bf(v2.y); d[10] = f2bf(v2.z); d[11] = f2bf(v2.w);
    d[12] = f2bf(v3.x); d[13] = f2bf(v3.y); d[14] = f2bf(v3.z); d[15] = f2bf(v3.w);
  }
  for (int idx = t; idx < 512; idx += 256) {  // k=1,2 slabs (rows of xg1/xg2)
    short8 v1 = *(const short8*)(xg1 + (size_t)n * 4096 + idx * 8);
    *(short8*)&Xs[1][idx >> 3][(idx & 7) * 8] = v1;
    short8 v2 = *(const short8*)(xg2 + (size_t)n * 4096 + idx * 8);
    *(short8*)&Xs[2][idx >> 3][(idx & 7) * 8] = v2;
  }
  for (int idx = t; idx < 1536; idx += 256) {  // weights: 24 chunks per o-row
    short8 v = *(const short8*)(W + (size_t)n * 12288 + idx * 8);
    int o = idx / 24, w8 = idx - o * 24;
    *(short8*)&Ws[o][w8 * 8] = v;
  }
  if (t < 64) {
    float acc = 0.0f;
#pragma unroll
    for (int d = 0; d < 16; d++)
      acc = fmaf(E[(size_t)n * EMB + d], bpool[d * 64 + t], acc);
    bias_s[t] = acc;
  }
  __syncthreads();

  int lane = t & 63, wave = t >> 6;
  int lr = lane & 15, lg = lane >> 4;
  int wb = wave * 16;
  floatx4 acc[4];
#pragma unroll
  for (int ot = 0; ot < 4; ot++) acc[ot] = (floatx4)0.0f;

#pragma unroll
  for (int ks = 0; ks < 6; ks++) {
    int kk = ks * 32 + lg * 8;
    short8 a = *(const short8*)&Xs[kk >> 6][wb + lr][kk & 63];
#pragma unroll
    for (int ot = 0; ot < 4; ot++) {
      short8 bb = *(const short8*)&Ws[ot * 16 + lr][kk];
      acc[ot] = __builtin_amdgcn_mfma_f32_16x16x32_bf16(a, bb, acc[ot], 0, 0, 0);
    }
  }
#pragma unroll
  for (int ot = 0; ot < 4; ot++) {
    int o = ot * 16 + lr;
    float bs = bias_s[o];
#pragma unroll
    for (int r = 0; r < 4; r++) {
      int b = wb + lg * 4 + r;
      out[((size_t)b * NNODES + n) * DOUT + o] = acc[ot][r] + bs;
    }
  }
}

// ---------------------------------------------------------------------------
extern "C" void kernel_launch(void* const* d_in, const int* in_sizes, int n_in,
                              void* d_out, int out_size, void* d_ws, size_t ws_size,
                              hipStream_t stream) {
  const float* x     = (const float*)d_in[0];  // (64,2048,64)
  const float* E     = (const float*)d_in[1];  // (2048,16)
  const float* pool  = (const float*)d_in[2];  // (16,3,64,64)
  const float* bpool = (const float*)d_in[3];  // (16,64)
  float* out = (float*)d_out;

  char* ws = (char*)d_ws;
  u16* Sb   = (u16*)(ws);                    // 2048*2048*2  = 8 MiB
  u16* xtt  = (u16*)(ws + 8388608);          // 4096*2048*2  = 16 MiB
  u16* xg1  = (u16*)(ws + 25165824);         // 2048*4096*2
  u16* xg1t = (u16*)(ws + 41943040);         // 4096*2048*2
  u16* xg2  = (u16*)(ws + 58720256);         // 2048*4096*2
  u16* Wall = (u16*)(ws + 75497472);         // 2048*12288*2 = 48 MiB  (end 120 MiB)
  // peff (16x12288 fp32, 768 KB) lives inside the xg2 region: xg2 is written
  // only by gemm2, which runs AFTER wgen2 has consumed peff. No extra ws.
  float* peff = (float*)(ws + 58720256);

  peff_k<<<768, 256, 0, stream>>>(pool, peff);
  adj_softmax<<<NNODES, 256, 0, stream>>>(E, Sb);
  trans_x<<<dim3(NNODES / 64, BATCH), 256, 0, stream>>>(x, xtt);
  wgen2<<<dim3(48, NNODES / 128), 256, 0, stream>>>(E, peff, Wall);
  // xg1[n][b*64+c] = sum_m S[n][m] * x[b][m][c]; also emits xg1t = xg1^T
  gemm_dp<<<dim3(32, 8), 512, 0, stream>>>(Sb, xtt, xg1, xg1t);
  // xg2[n][bc] = sum_m S[n][m] * xg1[m][bc]   (un-scaled; T2 folded into Weff)
  gemm_dp<<<dim3(32, 8), 512, 0, stream>>>(Sb, xg1t, xg2, nullptr);
  final_k<<<NNODES, 256, 0, stream>>>(x, E, bpool, xg1, xg2, Wall, out);
}

// Round 5
// 163.653 us; speedup vs baseline: 1.4780x; 1.0421x over previous
//
#include <hip/hip_runtime.h>
#include <hip/hip_bf16.h>

typedef unsigned short u16;
typedef short short8 __attribute__((ext_vector_type(8)));
typedef short short4v __attribute__((ext_vector_type(4)));
typedef float floatx4 __attribute__((ext_vector_type(4)));

#define NNODES 2048
#define BATCH  64
#define DIN    64
#define DOUT   64
#define EMB    16

__device__ __forceinline__ u16 f2bf(float f) {
  union { float f; unsigned u; } v; v.f = f;
  unsigned r = v.u + 0x7fffu + ((v.u >> 16) & 1u);
  return (u16)(r >> 16);
}

__device__ __forceinline__ void gload_lds16(const void* g, void* l) {
  __builtin_amdgcn_global_load_lds(
      (const __attribute__((address_space(1))) void*)g,
      (__attribute__((address_space(3))) void*)l, 16, 0, 0);
}

// ---------------------------------------------------------------------------
// Fused prologue: three independent input-only kernels in one dispatch.
//   blocks [0,2048):    adj_softmax row n         -> Sb
//   blocks [2048,4096): trans_x tile              -> xtt
//   blocks [4096,4864): peff reorder              -> peff
// ---------------------------------------------------------------------------
__global__ __launch_bounds__(256) void prologue(const float* __restrict__ E,
                                                const float* __restrict__ pool,
                                                const float* __restrict__ x,
                                                u16* __restrict__ Sb,
                                                u16* __restrict__ xtt,
                                                float* __restrict__ peff) {
  int bid = blockIdx.x;
  int t = threadIdx.x;

  if (bid < 2048) {
    // ---- S = softmax(relu(E E^T)) row n, bf16 out ----
    int n = bid;
    const float4* ep = (const float4*)(E + (size_t)n * EMB);
    float4 e0 = ep[0], e1 = ep[1], e2 = ep[2], e3 = ep[3];
    float lg[8];
    float mx = 0.0f;  // relu => all logits >= 0
#pragma unroll
    for (int j = 0; j < 8; j++) {
      int m = t + j * 256;
      const float4* mp = (const float4*)(E + (size_t)m * EMB);
      float4 a = mp[0], b = mp[1], c = mp[2], d = mp[3];
      float dot = e0.x * a.x + e0.y * a.y + e0.z * a.z + e0.w * a.w
                + e1.x * b.x + e1.y * b.y + e1.z * b.z + e1.w * b.w
                + e2.x * c.x + e2.y * c.y + e2.z * c.z + e2.w * c.w
                + e3.x * d.x + e3.y * d.y + e3.z * d.z + e3.w * d.w;
      dot = fmaxf(dot, 0.0f);
      lg[j] = dot;
      mx = fmaxf(mx, dot);
    }
    __shared__ float smax[4], ssum[4];
#pragma unroll
    for (int off = 32; off > 0; off >>= 1) mx = fmaxf(mx, __shfl_xor(mx, off, 64));
    if ((t & 63) == 0) smax[t >> 6] = mx;
    __syncthreads();
    mx = fmaxf(fmaxf(smax[0], smax[1]), fmaxf(smax[2], smax[3]));
    float sum = 0.0f;
#pragma unroll
    for (int j = 0; j < 8; j++) {
      float e = __expf(lg[j] - mx);
      lg[j] = e;
      sum += e;
    }
#pragma unroll
    for (int off = 32; off > 0; off >>= 1) sum += __shfl_xor(sum, off, 64);
    if ((t & 63) == 0) ssum[t >> 6] = sum;
    __syncthreads();
    sum = ssum[0] + ssum[1] + ssum[2] + ssum[3];
    float inv = 1.0f / sum;
#pragma unroll
    for (int j = 0; j < 8; j++)
      Sb[(size_t)n * NNODES + t + j * 256] = f2bf(lg[j] * inv);

  } else if (bid < 4096) {
    // ---- x (B,N,DIN) f32 -> xtt (B*64+c, N) bf16 ----
    __shared__ float tile[64][68];
    int u = bid - 2048;
    int b = u >> 5;
    int m0 = (u & 31) * 64;
    int r = t >> 2, cs = (t & 3) * 16;
    const float* xp = x + ((size_t)b * NNODES + m0 + r) * DIN + cs;
    float4 v0 = ((const float4*)xp)[0];
    float4 v1 = ((const float4*)xp)[1];
    float4 v2 = ((const float4*)xp)[2];
    float4 v3 = ((const float4*)xp)[3];
    *(float4*)&tile[r][cs]      = v0;
    *(float4*)&tile[r][cs + 4]  = v1;
    *(float4*)&tile[r][cs + 8]  = v2;
    *(float4*)&tile[r][cs + 12] = v3;
    __syncthreads();
    int c = t >> 2, ms = (t & 3) * 16;
    short8 o0, o1;
#pragma unroll
    for (int j = 0; j < 8; j++) o0[j] = (short)f2bf(tile[ms + j][c]);
#pragma unroll
    for (int j = 0; j < 8; j++) o1[j] = (short)f2bf(tile[ms + 8 + j][c]);
    u16* op = xtt + ((size_t)b * 64 + c) * NNODES + m0 + ms;
    *(short8*)op = o0;
    *(short8*)(op + 8) = o1;

  } else {
    // ---- peff[d][o*192 + k*64 + i] = pool_eff[d][k][i][o], fp32 ----
    int idx = (bid - 4096) * 256 + t;  // < 16*12288
    int d = idx / 12288;
    int r = idx - d * 12288;
    int o = r / 192;
    int ki = r - o * 192;
    int k = ki >> 6, i = ki & 63;
    float p = pool[(size_t)d * 12288 + k * 4096 + i * 64 + o];
    if (k == 0) p -= pool[(size_t)d * 12288 + 8192 + i * 64 + o];
    if (k == 2) p += p;
    peff[idx] = p;
  }
}

// ---------------------------------------------------------------------------
// W[n][e] = sum_d E[n][d] * peff[d][e]  (bf16 out), e = o*192 + k*64 + i
// ---------------------------------------------------------------------------
__global__ __launch_bounds__(256) void wgen2(const float* __restrict__ E,
                                             const float* __restrict__ peff,
                                             u16* __restrict__ W) {
  __shared__ float Es[128][17];
  int t = threadIdx.x;
  int n0 = blockIdx.y * 128;
  for (int idx = t; idx < 128 * EMB; idx += 256)
    Es[idx >> 4][idx & 15] = E[(size_t)n0 * EMB + idx];
  int e = blockIdx.x * 256 + t;
  float pv[16];
#pragma unroll
  for (int d = 0; d < 16; d++) pv[d] = peff[(size_t)d * 12288 + e];
  __syncthreads();
#pragma unroll 4
  for (int nn = 0; nn < 128; nn++) {
    float acc = 0.0f;
#pragma unroll
    for (int d = 0; d < 16; d++) acc = fmaf(Es[nn][d], pv[d], acc);
    W[(size_t)(n0 + nn) * 12288 + e] = f2bf(acc);
  }
}

// ---------------------------------------------------------------------------
// Deep-pipelined bf16 GEMM: C(2048 x 4096) = A(2048 x 2048) * Bt(4096 x 2048)^T
// BM=256, BN=128, BK=64. 512 threads = 8 waves (4M x 2N, 64x64 each).
// 3 LDS buffers, stage tile t+2 each iter, counted vmcnt(6) (never 0 in loop),
// raw s_barrier. XOR swizzle slot^(row&7) on both global source and ds_read
// addr (rule #21). Single-phase lockstep loop (R3 structure — the 2-phase
// split regressed, m196-style).
// If Ct != nullptr, also writes C^T via per-wave swizzled LDS transpose.
// ---------------------------------------------------------------------------
#define GK 2048      // K
#define GN 4096      // output cols
#define NT 32        // K / 64
#define BUFU 24576   // u16 per buffer: A 256*64=16384 + B 128*64=8192

__global__ __launch_bounds__(512) void gemm_dp(const u16* __restrict__ A,
                                               const u16* __restrict__ Bt,
                                               u16* __restrict__ C,
                                               u16* __restrict__ Ct) {
  __shared__ u16 smem[3 * BUFU];  // 147456 B
  int t = threadIdx.x, lane = t & 63, wave = t >> 6;

  // XCD-chunked bijective swizzle: grid = 32 x 8 = 256 (nwg % 8 == 0)
  int lin = blockIdx.y * gridDim.x + blockIdx.x;
  int nwg = gridDim.x * gridDim.y;
  int sw = (lin & 7) * (nwg >> 3) + (lin >> 3);
  int bx = sw & 31, by = sw >> 5;            // gridDim.x == 32
  int m0 = by * 256, n0 = bx * 128;

  // ---- staging address precompute: A 4 chunks, B 2 chunks per thread ----
  const u16* pg[6];
  int lof[6];
#pragma unroll
  for (int j = 0; j < 4; j++) {
    int c = t + 512 * j;
    int row = c >> 3;
    int gs = (c & 7) ^ (row & 7);
    pg[j] = A + (size_t)(m0 + row) * GK + gs * 8;
    lof[j] = c * 8;
  }
#pragma unroll
  for (int j = 0; j < 2; j++) {
    int c = t + 512 * j;
    int row = c >> 3;
    int gs = (c & 7) ^ (row & 7);
    pg[4 + j] = Bt + (size_t)(n0 + row) * GK + gs * 8;
    lof[4 + j] = 16384 + c * 8;
  }

  auto stage = [&](int b, int kt) {
#pragma unroll
    for (int j = 0; j < 6; j++)
      gload_lds16(pg[j] + kt, &smem[b * BUFU + lof[j]]);
  };

  // ---- per-wave fragment geometry ----
  int wr = wave >> 1, wc = wave & 1;   // 4M x 2N
  int lr = lane & 15, lg = lane >> 4;  // lg in 0..3

  floatx4 acc[4][4];
#pragma unroll
  for (int mi = 0; mi < 4; mi++)
#pragma unroll
    for (int ni = 0; ni < 4; ni++) acc[mi][ni] = (floatx4)0.0f;

  // precompute swizzled LDS u16-offsets for the 16 frag reads (per ksub s)
  int aoff[2][4], boff[2][4];
#pragma unroll
  for (int s = 0; s < 2; s++) {
#pragma unroll
    for (int mi = 0; mi < 4; mi++) {
      int row = wr * 64 + mi * 16 + lr;
      int slot = s * 4 + lg;
      aoff[s][mi] = row * 64 + (slot ^ (row & 7)) * 8;
    }
#pragma unroll
    for (int ni = 0; ni < 4; ni++) {
      int row = wc * 64 + ni * 16 + lr;
      int slot = s * 4 + lg;
      boff[s][ni] = 16384 + row * 64 + (slot ^ (row & 7)) * 8;
    }
  }

  auto compute = [&](int b) {
    const u16* base = &smem[b * BUFU];
    short8 af[2][4], bf[2][4];
#pragma unroll
    for (int s = 0; s < 2; s++) {
#pragma unroll
      for (int mi = 0; mi < 4; mi++) af[s][mi] = *(const short8*)(base + aoff[s][mi]);
#pragma unroll
      for (int ni = 0; ni < 4; ni++) bf[s][ni] = *(const short8*)(base + boff[s][ni]);
    }
#pragma unroll
    for (int s = 0; s < 2; s++)
#pragma unroll
      for (int mi = 0; mi < 4; mi++)
#pragma unroll
        for (int ni = 0; ni < 4; ni++)
          acc[mi][ni] = __builtin_amdgcn_mfma_f32_16x16x32_bf16(af[s][mi], bf[s][ni],
                                                                acc[mi][ni], 0, 0, 0);
  };

  // ---- prologue: stage tiles 0,1 ----
  stage(0, 0);
  stage(1, 64);

  // ---- main loop: tiles 0 .. NT-3 ----
  for (int tt = 0; tt < NT - 2; ++tt) {
    asm volatile("s_waitcnt vmcnt(6)" ::: "memory");  // own stage(tt) landed
    __builtin_amdgcn_s_barrier();                     // everyone's stage(tt) landed;
                                                      // all reads of buf (tt-1)%3 done
    stage((tt + 2) % 3, (tt + 2) * 64);               // 6 loads into the freed buffer
    compute(tt % 3);
  }
  // ---- tail: tile NT-2 (stage NT-1 still in flight), then NT-1 ----
  asm volatile("s_waitcnt vmcnt(6)" ::: "memory");
  __builtin_amdgcn_s_barrier();
  compute((NT - 2) % 3);
  asm volatile("s_waitcnt vmcnt(0)" ::: "memory");
  __builtin_amdgcn_s_barrier();
  compute((NT - 1) % 3);

  // ---- epilogue: row-major C ----
#pragma unroll
  for (int mi = 0; mi < 4; mi++)
#pragma unroll
    for (int ni = 0; ni < 4; ni++) {
      int row = m0 + wr * 64 + mi * 16 + lg * 4;
      int col = n0 + wc * 64 + ni * 16 + lr;
#pragma unroll
      for (int r = 0; r < 4; r++)
        C[(size_t)(row + r) * GN + col] = f2bf(acc[mi][ni][r]);
    }

  // ---- optional transposed epilogue: Ct[col][row], swizzled per-wave LDS ----
  if (Ct) {
    __syncthreads();  // all waves done reading the pipeline buffers
    u16* scr = smem + wave * 4096;  // [64 rows(ncol)][8 slots * 8 u16], 8 KB/wave
    // write acc transposed: row=ncol, chunk (mrow/8) stored at slot chunk^(ncol&7)
#pragma unroll
    for (int mi = 0; mi < 4; mi++)
#pragma unroll
      for (int ni = 0; ni < 4; ni++) {
        int ncol = ni * 16 + lr;
        int chunk = mi * 2 + (lg >> 1);
        int off = ncol * 64 + ((chunk ^ (ncol & 7)) << 3) + (lg & 1) * 4;
        short4v sv;
#pragma unroll
        for (int r = 0; r < 4; r++) sv[r] = (short)f2bf(acc[mi][ni][r]);
        *(short4v*)&scr[off] = sv;
      }
    // lane c reads row c (chunk jj at slot jj^(c&7)), stores 128B to Ct row.
    // per-wave private scratch: compiler's lgkmcnt orders own-wave ds ops.
    int c = lane;
    u16* op = Ct + (size_t)(n0 + wc * 64 + c) * GK + m0 + wr * 64;
#pragma unroll
    for (int jj = 0; jj < 8; jj++) {
      short8 v = *(const short8*)&scr[c * 64 + ((jj ^ (c & 7)) << 3)];
      *(short8*)(op + jj * 8) = v;
    }
  }
}

// ---------------------------------------------------------------------------
// Final per-node fused GEMM: out[b,n,o] = sum_kk A[b,kk]*Weff[n,kk,o] + bias[n,o]
// ---------------------------------------------------------------------------
__global__ __launch_bounds__(256) void final_k(const float* __restrict__ x,
                                               const float* __restrict__ E,
                                               const float* __restrict__ bpool,
                                               const u16* __restrict__ xg1,
                                               const u16* __restrict__ xg2,
                                               const u16* __restrict__ W,
                                               float* __restrict__ out) {
  __shared__ u16 Xs[3][64][72];   // [k][b][i], +8 pad: 2-way banks only
  __shared__ u16 Ws[64][200];     // [o][k*64+i], +8 pad
  __shared__ float bias_s[64];
  int n = blockIdx.x, t = threadIdx.x;

  {  // stage k=0 slab from fp32 x
    int b = t >> 2, i0 = (t & 3) * 16;
    const float* xp = x + ((size_t)b * NNODES + n) * DIN + i0;
    float4 v0 = ((const float4*)xp)[0];
    float4 v1 = ((const float4*)xp)[1];
    float4 v2 = ((const float4*)xp)[2];
    float4 v3 = ((const float4*)xp)[3];
    u16* d = &Xs[0][b][i0];
    d[0] = f2bf(v0.x); d[1] = f2bf(v0.y); d[2] = f2bf(v0.z); d[3] = f2bf(v0.w);
    d[4] = f2bf(v1.x); d[5] = f2bf(v1.y); d[6] = f2bf(v1.z); d[7] = f2bf(v1.w);
    d[8] = f2bf(v2.x); d[9] = f2bf(v2.y); d[10] = f2bf(v2.z); d[11] = f2bf(v2.w);
    d[12] = f2bf(v3.x); d[13] = f2bf(v3.y); d[14] = f2bf(v3.z); d[15] = f2bf(v3.w);
  }
  for (int idx = t; idx < 512; idx += 256) {  // k=1,2 slabs (rows of xg1/xg2)
    short8 v1 = *(const short8*)(xg1 + (size_t)n * 4096 + idx * 8);
    *(short8*)&Xs[1][idx >> 3][(idx & 7) * 8] = v1;
    short8 v2 = *(const short8*)(xg2 + (size_t)n * 4096 + idx * 8);
    *(short8*)&Xs[2][idx >> 3][(idx & 7) * 8] = v2;
  }
  for (int idx = t; idx < 1536; idx += 256) {  // weights: 24 chunks per o-row
    short8 v = *(const short8*)(W + (size_t)n * 12288 + idx * 8);
    int o = idx / 24, w8 = idx - o * 24;
    *(short8*)&Ws[o][w8 * 8] = v;
  }
  if (t < 64) {
    float acc = 0.0f;
#pragma unroll
    for (int d = 0; d < 16; d++)
      acc = fmaf(E[(size_t)n * EMB + d], bpool[d * 64 + t], acc);
    bias_s[t] = acc;
  }
  __syncthreads();

  int lane = t & 63, wave = t >> 6;
  int lr = lane & 15, lg = lane >> 4;
  int wb = wave * 16;
  floatx4 acc[4];
#pragma unroll
  for (int ot = 0; ot < 4; ot++) acc[ot] = (floatx4)0.0f;

#pragma unroll
  for (int ks = 0; ks < 6; ks++) {
    int kk = ks * 32 + lg * 8;
    short8 a = *(const short8*)&Xs[kk >> 6][wb + lr][kk & 63];
#pragma unroll
    for (int ot = 0; ot < 4; ot++) {
      short8 bb = *(const short8*)&Ws[ot * 16 + lr][kk];
      acc[ot] = __builtin_amdgcn_mfma_f32_16x16x32_bf16(a, bb, acc[ot], 0, 0, 0);
    }
  }
#pragma unroll
  for (int ot = 0; ot < 4; ot++) {
    int o = ot * 16 + lr;
    float bs = bias_s[o];
#pragma unroll
    for (int r = 0; r < 4; r++) {
      int b = wb + lg * 4 + r;
      out[((size_t)b * NNODES + n) * DOUT + o] = acc[ot][r] + bs;
    }
  }
}

// ---------------------------------------------------------------------------
extern "C" void kernel_launch(void* const* d_in, const int* in_sizes, int n_in,
                              void* d_out, int out_size, void* d_ws, size_t ws_size,
                              hipStream_t stream) {
  const float* x     = (const float*)d_in[0];  // (64,2048,64)
  const float* E     = (const float*)d_in[1];  // (2048,16)
  const float* pool  = (const float*)d_in[2];  // (16,3,64,64)
  const float* bpool = (const float*)d_in[3];  // (16,64)
  float* out = (float*)d_out;

  char* ws = (char*)d_ws;
  u16* Sb   = (u16*)(ws);                    // 2048*2048*2  = 8 MiB
  u16* xtt  = (u16*)(ws + 8388608);          // 4096*2048*2  = 16 MiB
  u16* xg1  = (u16*)(ws + 25165824);         // 2048*4096*2
  u16* xg1t = (u16*)(ws + 41943040);         // 4096*2048*2
  u16* xg2  = (u16*)(ws + 58720256);         // 2048*4096*2
  u16* Wall = (u16*)(ws + 75497472);         // 2048*12288*2 = 48 MiB  (end 120 MiB)
  // peff (16x12288 fp32, 768 KB) lives inside the xg2 region: xg2 is written
  // only by gemm2, which runs AFTER wgen2 has consumed peff. No extra ws.
  float* peff = (float*)(ws + 58720256);

  // fused: adj_softmax (2048 blocks) + trans_x (2048) + peff reorder (768)
  prologue<<<4864, 256, 0, stream>>>(E, pool, x, Sb, xtt, peff);
  wgen2<<<dim3(48, NNODES / 128), 256, 0, stream>>>(E, peff, Wall);
  // xg1[n][b*64+c] = sum_m S[n][m] * x[b][m][c]; also emits xg1t = xg1^T
  gemm_dp<<<dim3(32, 8), 512, 0, stream>>>(Sb, xtt, xg1, xg1t);
  // xg2[n][bc] = sum_m S[n][m] * xg1[m][bc]   (un-scaled; T2 folded into Weff)
  gemm_dp<<<dim3(32, 8), 512, 0, stream>>>(Sb, xg1t, xg2, nullptr);
  final_k<<<NNODES, 256, 0, stream>>>(x, E, bpool, xg1, xg2, Wall, out);
}

// Round 6
// 163.427 us; speedup vs baseline: 1.4800x; 1.0014x over previous
//
#include <hip/hip_runtime.h>
#include <hip/hip_bf16.h>

typedef unsigned short u16;
typedef short short8 __attribute__((ext_vector_type(8)));
typedef short short4v __attribute__((ext_vector_type(4)));
typedef float floatx4 __attribute__((ext_vector_type(4)));

#define NNODES 2048
#define BATCH  64
#define DIN    64
#define DOUT   64
#define EMB    16

__device__ __forceinline__ u16 f2bf(float f) {
  union { float f; unsigned u; } v; v.f = f;
  unsigned r = v.u + 0x7fffu + ((v.u >> 16) & 1u);
  return (u16)(r >> 16);
}

__device__ __forceinline__ void gload_lds16(const void* g, void* l) {
  __builtin_amdgcn_global_load_lds(
      (const __attribute__((address_space(1))) void*)g,
      (__attribute__((address_space(3))) void*)l, 16, 0, 0);
}

// ---------------------------------------------------------------------------
// Fused prologue: three independent input-only kernels in one dispatch.
//   blocks [0,2048):    adj_softmax row n         -> Sb
//   blocks [2048,4096): trans_x tile              -> xtt
//   blocks [4096,4864): peff reorder              -> peff
// ---------------------------------------------------------------------------
__global__ __launch_bounds__(256) void prologue(const float* __restrict__ E,
                                                const float* __restrict__ pool,
                                                const float* __restrict__ x,
                                                u16* __restrict__ Sb,
                                                u16* __restrict__ xtt,
                                                float* __restrict__ peff) {
  int bid = blockIdx.x;
  int t = threadIdx.x;

  if (bid < 2048) {
    // ---- S = softmax(relu(E E^T)) row n, bf16 out ----
    int n = bid;
    const float4* ep = (const float4*)(E + (size_t)n * EMB);
    float4 e0 = ep[0], e1 = ep[1], e2 = ep[2], e3 = ep[3];
    float lg[8];
    float mx = 0.0f;  // relu => all logits >= 0
#pragma unroll
    for (int j = 0; j < 8; j++) {
      int m = t + j * 256;
      const float4* mp = (const float4*)(E + (size_t)m * EMB);
      float4 a = mp[0], b = mp[1], c = mp[2], d = mp[3];
      float dot = e0.x * a.x + e0.y * a.y + e0.z * a.z + e0.w * a.w
                + e1.x * b.x + e1.y * b.y + e1.z * b.z + e1.w * b.w
                + e2.x * c.x + e2.y * c.y + e2.z * c.z + e2.w * c.w
                + e3.x * d.x + e3.y * d.y + e3.z * d.z + e3.w * d.w;
      dot = fmaxf(dot, 0.0f);
      lg[j] = dot;
      mx = fmaxf(mx, dot);
    }
    __shared__ float smax[4], ssum[4];
#pragma unroll
    for (int off = 32; off > 0; off >>= 1) mx = fmaxf(mx, __shfl_xor(mx, off, 64));
    if ((t & 63) == 0) smax[t >> 6] = mx;
    __syncthreads();
    mx = fmaxf(fmaxf(smax[0], smax[1]), fmaxf(smax[2], smax[3]));
    float sum = 0.0f;
#pragma unroll
    for (int j = 0; j < 8; j++) {
      float e = __expf(lg[j] - mx);
      lg[j] = e;
      sum += e;
    }
#pragma unroll
    for (int off = 32; off > 0; off >>= 1) sum += __shfl_xor(sum, off, 64);
    if ((t & 63) == 0) ssum[t >> 6] = sum;
    __syncthreads();
    sum = ssum[0] + ssum[1] + ssum[2] + ssum[3];
    float inv = 1.0f / sum;
#pragma unroll
    for (int j = 0; j < 8; j++)
      Sb[(size_t)n * NNODES + t + j * 256] = f2bf(lg[j] * inv);

  } else if (bid < 4096) {
    // ---- x (B,N,DIN) f32 -> xtt (B*64+c, N) bf16 ----
    __shared__ float tile[64][68];
    int u = bid - 2048;
    int b = u >> 5;
    int m0 = (u & 31) * 64;
    int r = t >> 2, cs = (t & 3) * 16;
    const float* xp = x + ((size_t)b * NNODES + m0 + r) * DIN + cs;
    float4 v0 = ((const float4*)xp)[0];
    float4 v1 = ((const float4*)xp)[1];
    float4 v2 = ((const float4*)xp)[2];
    float4 v3 = ((const float4*)xp)[3];
    *(float4*)&tile[r][cs]      = v0;
    *(float4*)&tile[r][cs + 4]  = v1;
    *(float4*)&tile[r][cs + 8]  = v2;
    *(float4*)&tile[r][cs + 12] = v3;
    __syncthreads();
    int c = t >> 2, ms = (t & 3) * 16;
    short8 o0, o1;
#pragma unroll
    for (int j = 0; j < 8; j++) o0[j] = (short)f2bf(tile[ms + j][c]);
#pragma unroll
    for (int j = 0; j < 8; j++) o1[j] = (short)f2bf(tile[ms + 8 + j][c]);
    u16* op = xtt + ((size_t)b * 64 + c) * NNODES + m0 + ms;
    *(short8*)op = o0;
    *(short8*)(op + 8) = o1;

  } else {
    // ---- peff[d][o*192 + k*64 + i] = pool_eff[d][k][i][o], fp32 ----
    int idx = (bid - 4096) * 256 + t;  // < 16*12288
    int d = idx / 12288;
    int r = idx - d * 12288;
    int o = r / 192;
    int ki = r - o * 192;
    int k = ki >> 6, i = ki & 63;
    float p = pool[(size_t)d * 12288 + k * 4096 + i * 64 + o];
    if (k == 0) p -= pool[(size_t)d * 12288 + 8192 + i * 64 + o];
    if (k == 2) p += p;
    peff[idx] = p;
  }
}

// ---------------------------------------------------------------------------
// W[n][e] = sum_d E[n][d] * peff[d][e]  (bf16 out), e = o*192 + k*64 + i
// ---------------------------------------------------------------------------
__global__ __launch_bounds__(256) void wgen2(const float* __restrict__ E,
                                             const float* __restrict__ peff,
                                             u16* __restrict__ W) {
  __shared__ float Es[128][17];
  int t = threadIdx.x;
  int n0 = blockIdx.y * 128;
  for (int idx = t; idx < 128 * EMB; idx += 256)
    Es[idx >> 4][idx & 15] = E[(size_t)n0 * EMB + idx];
  int e = blockIdx.x * 256 + t;
  float pv[16];
#pragma unroll
  for (int d = 0; d < 16; d++) pv[d] = peff[(size_t)d * 12288 + e];
  __syncthreads();
#pragma unroll 4
  for (int nn = 0; nn < 128; nn++) {
    float acc = 0.0f;
#pragma unroll
    for (int d = 0; d < 16; d++) acc = fmaf(Es[nn][d], pv[d], acc);
    W[(size_t)(n0 + nn) * 12288 + e] = f2bf(acc);
  }
}

// ---------------------------------------------------------------------------
// Deep-pipelined bf16 GEMM (R3 lockstep structure, PROVEN 39 us / 0 conflicts):
// C(2048 x 4096) = A(2048 x 2048) * Bt(4096 x 2048)^T.
// BM=256, BN=128, BK=64. 512 threads = 8 waves (4M x 2N, 64x64 each).
// 3 LDS buffers, stage tile t+2 each iter, counted vmcnt(6), raw s_barrier.
// XOR swizzle slot^(row&7) on both global source and ds_read addr (rule #21).
//
// TWO physically separate kernels: gemm_plain (no transpose code AT ALL — the
// mere presence of the epilogue was shown in R5 to poison main-loop codegen:
// VGPR 92->100, in-loop bank conflicts 0->196K, 39->45 us) and gemm_tr
// (same loop + transposed-output epilogue for the xg1/xg1t double write).
// ---------------------------------------------------------------------------
#define GK 2048      // K
#define GN 4096      // output cols
#define NT 32        // K / 64
#define BUFU 24576   // u16 per buffer: A 256*64=16384 + B 128*64=8192

#define GEMM_PREAMBLE                                                          \
  __shared__ u16 smem[3 * BUFU];                                               \
  int t = threadIdx.x, lane = t & 63, wave = t >> 6;                           \
  int lin = blockIdx.y * gridDim.x + blockIdx.x;                               \
  int nwg = gridDim.x * gridDim.y;                                             \
  int sw = (lin & 7) * (nwg >> 3) + (lin >> 3);                                \
  int bx = sw & 31, by = sw >> 5;                                              \
  int m0 = by * 256, n0 = bx * 128;                                            \
  const u16* pg[6];                                                            \
  int lof[6];                                                                  \
  _Pragma("unroll") for (int j = 0; j < 4; j++) {                              \
    int c = t + 512 * j;                                                       \
    int row = c >> 3;                                                          \
    int gs = (c & 7) ^ (row & 7);                                              \
    pg[j] = A + (size_t)(m0 + row) * GK + gs * 8;                              \
    lof[j] = c * 8;                                                            \
  }                                                                            \
  _Pragma("unroll") for (int j = 0; j < 2; j++) {                              \
    int c = t + 512 * j;                                                       \
    int row = c >> 3;                                                          \
    int gs = (c & 7) ^ (row & 7);                                              \
    pg[4 + j] = Bt + (size_t)(n0 + row) * GK + gs * 8;                         \
    lof[4 + j] = 16384 + c * 8;                                                \
  }                                                                            \
  auto stage = [&](int b, int kt) {                                            \
    _Pragma("unroll") for (int j = 0; j < 6; j++)                              \
        gload_lds16(pg[j] + kt, &smem[b * BUFU + lof[j]]);                     \
  };                                                                           \
  int wr = wave >> 1, wc = wave & 1;                                           \
  int lr = lane & 15, lg = lane >> 4;                                          \
  floatx4 acc[4][4];                                                           \
  _Pragma("unroll") for (int mi = 0; mi < 4; mi++)                             \
      _Pragma("unroll") for (int ni = 0; ni < 4; ni++)                         \
          acc[mi][ni] = (floatx4)0.0f;                                         \
  int aoff[2][4], boff[2][4];                                                  \
  _Pragma("unroll") for (int s = 0; s < 2; s++) {                              \
    _Pragma("unroll") for (int mi = 0; mi < 4; mi++) {                         \
      int row = wr * 64 + mi * 16 + lr;                                        \
      int slot = s * 4 + lg;                                                   \
      aoff[s][mi] = row * 64 + (slot ^ (row & 7)) * 8;                         \
    }                                                                          \
    _Pragma("unroll") for (int ni = 0; ni < 4; ni++) {                         \
      int row = wc * 64 + ni * 16 + lr;                                        \
      int slot = s * 4 + lg;                                                   \
      boff[s][ni] = 16384 + row * 64 + (slot ^ (row & 7)) * 8;                 \
    }                                                                          \
  }                                                                            \
  auto compute = [&](int b) {                                                  \
    const u16* base = &smem[b * BUFU];                                         \
    short8 af[2][4], bf[2][4];                                                 \
    _Pragma("unroll") for (int s = 0; s < 2; s++) {                            \
      _Pragma("unroll") for (int mi = 0; mi < 4; mi++)                         \
          af[s][mi] = *(const short8*)(base + aoff[s][mi]);                    \
      _Pragma("unroll") for (int ni = 0; ni < 4; ni++)                         \
          bf[s][ni] = *(const short8*)(base + boff[s][ni]);                    \
    }                                                                          \
    _Pragma("unroll") for (int s = 0; s < 2; s++)                              \
        _Pragma("unroll") for (int mi = 0; mi < 4; mi++)                       \
            _Pragma("unroll") for (int ni = 0; ni < 4; ni++)                   \
                acc[mi][ni] = __builtin_amdgcn_mfma_f32_16x16x32_bf16(         \
                    af[s][mi], bf[s][ni], acc[mi][ni], 0, 0, 0);               \
  };                                                                           \
  stage(0, 0);                                                                 \
  stage(1, 64);                                                                \
  for (int tt = 0; tt < NT - 2; ++tt) {                                        \
    asm volatile("s_waitcnt vmcnt(6)" ::: "memory");                           \
    __builtin_amdgcn_s_barrier();                                              \
    stage((tt + 2) % 3, (tt + 2) * 64);                                        \
    compute(tt % 3);                                                           \
  }                                                                            \
  asm volatile("s_waitcnt vmcnt(6)" ::: "memory");                             \
  __builtin_amdgcn_s_barrier();                                                \
  compute((NT - 2) % 3);                                                       \
  asm volatile("s_waitcnt vmcnt(0)" ::: "memory");                             \
  __builtin_amdgcn_s_barrier();                                                \
  compute((NT - 1) % 3);                                                       \
  _Pragma("unroll") for (int mi = 0; mi < 4; mi++)                             \
      _Pragma("unroll") for (int ni = 0; ni < 4; ni++) {                       \
    int row = m0 + wr * 64 + mi * 16 + lg * 4;                                 \
    int col = n0 + wc * 64 + ni * 16 + lr;                                     \
    _Pragma("unroll") for (int r = 0; r < 4; r++)                              \
        C[(size_t)(row + r) * GN + col] = f2bf(acc[mi][ni][r]);                \
  }

__global__ __launch_bounds__(512) void gemm_plain(const u16* __restrict__ A,
                                                  const u16* __restrict__ Bt,
                                                  u16* __restrict__ C) {
  GEMM_PREAMBLE
}

__global__ __launch_bounds__(512) void gemm_tr(const u16* __restrict__ A,
                                               const u16* __restrict__ Bt,
                                               u16* __restrict__ C,
                                               u16* __restrict__ Ct) {
  GEMM_PREAMBLE
  // ---- transposed epilogue: Ct[col][row], swizzled per-wave LDS scratch ----
  __syncthreads();  // all waves done reading the pipeline buffers
  u16* scr = smem + wave * 4096;  // [64 rows(ncol)][8 slots * 8 u16], 8 KB/wave
#pragma unroll
  for (int mi = 0; mi < 4; mi++)
#pragma unroll
    for (int ni = 0; ni < 4; ni++) {
      int ncol = ni * 16 + lr;
      int chunk = mi * 2 + (lg >> 1);
      int off = ncol * 64 + ((chunk ^ (ncol & 7)) << 3) + (lg & 1) * 4;
      short4v sv;
#pragma unroll
      for (int r = 0; r < 4; r++) sv[r] = (short)f2bf(acc[mi][ni][r]);
      *(short4v*)&scr[off] = sv;
    }
  // lane c reads row c (chunk jj at slot jj^(c&7)), stores 128B to Ct row.
  int c = lane;
  u16* op = Ct + (size_t)(n0 + wc * 64 + c) * GK + m0 + wr * 64;
#pragma unroll
  for (int jj = 0; jj < 8; jj++) {
    short8 v = *(const short8*)&scr[c * 64 + ((jj ^ (c & 7)) << 3)];
    *(short8*)(op + jj * 8) = v;
  }
}

// ---------------------------------------------------------------------------
// Final per-node fused GEMM: out[b,n,o] = sum_kk A[b,kk]*Weff[n,kk,o] + bias[n,o]
// ---------------------------------------------------------------------------
__global__ __launch_bounds__(256) void final_k(const float* __restrict__ x,
                                               const float* __restrict__ E,
                                               const float* __restrict__ bpool,
                                               const u16* __restrict__ xg1,
                                               const u16* __restrict__ xg2,
                                               const u16* __restrict__ W,
                                               float* __restrict__ out) {
  __shared__ u16 Xs[3][64][72];   // [k][b][i], +8 pad: 2-way banks only
  __shared__ u16 Ws[64][200];     // [o][k*64+i], +8 pad
  __shared__ float bias_s[64];
  int n = blockIdx.x, t = threadIdx.x;

  {  // stage k=0 slab from fp32 x
    int b = t >> 2, i0 = (t & 3) * 16;
    const float* xp = x + ((size_t)b * NNODES + n) * DIN + i0;
    float4 v0 = ((const float4*)xp)[0];
    float4 v1 = ((const float4*)xp)[1];
    float4 v2 = ((const float4*)xp)[2];
    float4 v3 = ((const float4*)xp)[3];
    u16* d = &Xs[0][b][i0];
    d[0] = f2bf(v0.x); d[1] = f2bf(v0.y); d[2] = f2bf(v0.z); d[3] = f2bf(v0.w);
    d[4] = f2bf(v1.x); d[5] = f2bf(v1.y); d[6] = f2bf(v1.z); d[7] = f2bf(v1.w);
    d[8] = f2bf(v2.x); d[9] = f2bf(v2.y); d[10] = f2bf(v2.z); d[11] = f2bf(v2.w);
    d[12] = f2bf(v3.x); d[13] = f2bf(v3.y); d[14] = f2bf(v3.z); d[15] = f2bf(v3.w);
  }
  for (int idx = t; idx < 512; idx += 256) {  // k=1,2 slabs (rows of xg1/xg2)
    short8 v1 = *(const short8*)(xg1 + (size_t)n * 4096 + idx * 8);
    *(short8*)&Xs[1][idx >> 3][(idx & 7) * 8] = v1;
    short8 v2 = *(const short8*)(xg2 + (size_t)n * 4096 + idx * 8);
    *(short8*)&Xs[2][idx >> 3][(idx & 7) * 8] = v2;
  }
  for (int idx = t; idx < 1536; idx += 256) {  // weights: 24 chunks per o-row
    short8 v = *(const short8*)(W + (size_t)n * 12288 + idx * 8);
    int o = idx / 24, w8 = idx - o * 24;
    *(short8*)&Ws[o][w8 * 8] = v;
  }
  if (t < 64) {
    float acc = 0.0f;
#pragma unroll
    for (int d = 0; d < 16; d++)
      acc = fmaf(E[(size_t)n * EMB + d], bpool[d * 64 + t], acc);
    bias_s[t] = acc;
  }
  __syncthreads();

  int lane = t & 63, wave = t >> 6;
  int lr = lane & 15, lg = lane >> 4;
  int wb = wave * 16;
  floatx4 acc[4];
#pragma unroll
  for (int ot = 0; ot < 4; ot++) acc[ot] = (floatx4)0.0f;

#pragma unroll
  for (int ks = 0; ks < 6; ks++) {
    int kk = ks * 32 + lg * 8;
    short8 a = *(const short8*)&Xs[kk >> 6][wb + lr][kk & 63];
#pragma unroll
    for (int ot = 0; ot < 4; ot++) {
      short8 bb = *(const short8*)&Ws[ot * 16 + lr][kk];
      acc[ot] = __builtin_amdgcn_mfma_f32_16x16x32_bf16(a, bb, acc[ot], 0, 0, 0);
    }
  }
#pragma unroll
  for (int ot = 0; ot < 4; ot++) {
    int o = ot * 16 + lr;
    float bs = bias_s[o];
#pragma unroll
    for (int r = 0; r < 4; r++) {
      int b = wb + lg * 4 + r;
      out[((size_t)b * NNODES + n) * DOUT + o] = acc[ot][r] + bs;
    }
  }
}

// ---------------------------------------------------------------------------
extern "C" void kernel_launch(void* const* d_in, const int* in_sizes, int n_in,
                              void* d_out, int out_size, void* d_ws, size_t ws_size,
                              hipStream_t stream) {
  const float* x     = (const float*)d_in[0];  // (64,2048,64)
  const float* E     = (const float*)d_in[1];  // (2048,16)
  const float* pool  = (const float*)d_in[2];  // (16,3,64,64)
  const float* bpool = (const float*)d_in[3];  // (16,64)
  float* out = (float*)d_out;

  char* ws = (char*)d_ws;
  u16* Sb   = (u16*)(ws);                    // 2048*2048*2  = 8 MiB
  u16* xtt  = (u16*)(ws + 8388608);          // 4096*2048*2  = 16 MiB
  u16* xg1  = (u16*)(ws + 25165824);         // 2048*4096*2
  u16* xg1t = (u16*)(ws + 41943040);         // 4096*2048*2
  u16* xg2  = (u16*)(ws + 58720256);         // 2048*4096*2
  u16* Wall = (u16*)(ws + 75497472);         // 2048*12288*2 = 48 MiB  (end 120 MiB)
  // peff (16x12288 fp32, 768 KB) lives inside the xg2 region: xg2 is written
  // only by gemm2, which runs AFTER wgen2 has consumed peff. No extra ws.
  float* peff = (float*)(ws + 58720256);

  // fused: adj_softmax (2048 blocks) + trans_x (2048) + peff reorder (768)
  prologue<<<4864, 256, 0, stream>>>(E, pool, x, Sb, xtt, peff);
  wgen2<<<dim3(48, NNODES / 128), 256, 0, stream>>>(E, peff, Wall);
  // xg1[n][b*64+c] = sum_m S[n][m] * x[b][m][c]; also emits xg1t = xg1^T
  gemm_tr<<<dim3(32, 8), 512, 0, stream>>>(Sb, xtt, xg1, xg1t);
  // xg2[n][bc] = sum_m S[n][m] * xg1[m][bc]   (un-scaled; T2 folded into Weff)
  gemm_plain<<<dim3(32, 8), 512, 0, stream>>>(Sb, xg1t, xg2);
  final_k<<<NNODES, 256, 0, stream>>>(x, E, bpool, xg1, xg2, Wall, out);
}

// Round 7
// 154.695 us; speedup vs baseline: 1.5635x; 1.0564x over previous
//
#include <hip/hip_runtime.h>
#include <hip/hip_bf16.h>

typedef unsigned short u16;
typedef short short8 __attribute__((ext_vector_type(8)));
typedef short short4v __attribute__((ext_vector_type(4)));
typedef float floatx4 __attribute__((ext_vector_type(4)));

#define NNODES 2048
#define BATCH  64
#define DIN    64
#define DOUT   64
#define EMB    16

__device__ __forceinline__ u16 f2bf(float f) {
  union { float f; unsigned u; } v; v.f = f;
  unsigned r = v.u + 0x7fffu + ((v.u >> 16) & 1u);
  return (u16)(r >> 16);
}

__device__ __forceinline__ void gload_lds16(const void* g, void* l) {
  __builtin_amdgcn_global_load_lds(
      (const __attribute__((address_space(1))) void*)g,
      (__attribute__((address_space(3))) void*)l, 16, 0, 0);
}

// ---------------------------------------------------------------------------
// Fused prologue: four independent input-only jobs in one dispatch.
//   blocks [0,768):     wgen (native layout)  -> Wall   (heaviest: first)
//   blocks [768,2816):  adj_softmax row n     -> Sb
//   blocks [2816,4864): trans_x tile          -> xtt
// wgen: W[n][e'] = sum_d E[n][d]*pool_eff[d][e'], e' = k*4096+i*64+o (native).
// pool_eff folds T0/T2: k0 -> p0 - p2 ; k2 -> 2*p2. Coalesced pool reads, no
// peff intermediate, no separate wgen2 dispatch.
// ---------------------------------------------------------------------------
__global__ __launch_bounds__(256) void prologue(const float* __restrict__ E,
                                                const float* __restrict__ pool,
                                                const float* __restrict__ x,
                                                u16* __restrict__ Sb,
                                                u16* __restrict__ xtt,
                                                u16* __restrict__ W) {
  int bid = blockIdx.x;
  int t = threadIdx.x;

  if (bid < 768) {
    // ---- weight generation, native (k,i,o) order ----
    __shared__ float Es[128][17];
    int ec = bid % 48, nc = bid / 48;
    int e = ec * 256 + t;            // e' = k*4096 + i*64 + o
    int n0 = nc * 128;
    for (int idx = t; idx < 128 * EMB; idx += 256)
      Es[idx >> 4][idx & 15] = E[(size_t)n0 * EMB + idx];
    float pv[16];
#pragma unroll
    for (int d = 0; d < 16; d++) {
      float p = pool[(size_t)d * 12288 + e];
      if (e < 4096) p -= pool[(size_t)d * 12288 + 8192 + e];
      if (e >= 8192) p += p;
      pv[d] = p;
    }
    __syncthreads();
#pragma unroll 4
    for (int nn = 0; nn < 128; nn++) {
      float acc = 0.0f;
#pragma unroll
      for (int d = 0; d < 16; d++) acc = fmaf(Es[nn][d], pv[d], acc);
      W[(size_t)(n0 + nn) * 12288 + e] = f2bf(acc);
    }

  } else if (bid < 2816) {
    // ---- S = softmax(relu(E E^T)) row n, bf16 out ----
    int n = bid - 768;
    const float4* ep = (const float4*)(E + (size_t)n * EMB);
    float4 e0 = ep[0], e1 = ep[1], e2 = ep[2], e3 = ep[3];
    float lg[8];
    float mx = 0.0f;  // relu => all logits >= 0
#pragma unroll
    for (int j = 0; j < 8; j++) {
      int m = t + j * 256;
      const float4* mp = (const float4*)(E + (size_t)m * EMB);
      float4 a = mp[0], b = mp[1], c = mp[2], d = mp[3];
      float dot = e0.x * a.x + e0.y * a.y + e0.z * a.z + e0.w * a.w
                + e1.x * b.x + e1.y * b.y + e1.z * b.z + e1.w * b.w
                + e2.x * c.x + e2.y * c.y + e2.z * c.z + e2.w * c.w
                + e3.x * d.x + e3.y * d.y + e3.z * d.z + e3.w * d.w;
      dot = fmaxf(dot, 0.0f);
      lg[j] = dot;
      mx = fmaxf(mx, dot);
    }
    __shared__ float smax[4], ssum[4];
#pragma unroll
    for (int off = 32; off > 0; off >>= 1) mx = fmaxf(mx, __shfl_xor(mx, off, 64));
    if ((t & 63) == 0) smax[t >> 6] = mx;
    __syncthreads();
    mx = fmaxf(fmaxf(smax[0], smax[1]), fmaxf(smax[2], smax[3]));
    float sum = 0.0f;
#pragma unroll
    for (int j = 0; j < 8; j++) {
      float e = __expf(lg[j] - mx);
      lg[j] = e;
      sum += e;
    }
#pragma unroll
    for (int off = 32; off > 0; off >>= 1) sum += __shfl_xor(sum, off, 64);
    if ((t & 63) == 0) ssum[t >> 6] = sum;
    __syncthreads();
    sum = ssum[0] + ssum[1] + ssum[2] + ssum[3];
    float inv = 1.0f / sum;
#pragma unroll
    for (int j = 0; j < 8; j++)
      Sb[(size_t)n * NNODES + t + j * 256] = f2bf(lg[j] * inv);

  } else {
    // ---- x (B,N,DIN) f32 -> xtt (B*64+c, N) bf16 ----
    __shared__ float tile[64][68];
    int u = bid - 2816;
    int b = u >> 5;
    int m0 = (u & 31) * 64;
    int r = t >> 2, cs = (t & 3) * 16;
    const float* xp = x + ((size_t)b * NNODES + m0 + r) * DIN + cs;
    float4 v0 = ((const float4*)xp)[0];
    float4 v1 = ((const float4*)xp)[1];
    float4 v2 = ((const float4*)xp)[2];
    float4 v3 = ((const float4*)xp)[3];
    *(float4*)&tile[r][cs]      = v0;
    *(float4*)&tile[r][cs + 4]  = v1;
    *(float4*)&tile[r][cs + 8]  = v2;
    *(float4*)&tile[r][cs + 12] = v3;
    __syncthreads();
    int c = t >> 2, ms = (t & 3) * 16;
    short8 o0, o1;
#pragma unroll
    for (int j = 0; j < 8; j++) o0[j] = (short)f2bf(tile[ms + j][c]);
#pragma unroll
    for (int j = 0; j < 8; j++) o1[j] = (short)f2bf(tile[ms + 8 + j][c]);
    u16* op = xtt + ((size_t)b * 64 + c) * NNODES + m0 + ms;
    *(short8*)op = o0;
    *(short8*)(op + 8) = o1;
  }
}

// ---------------------------------------------------------------------------
// Deep-pipelined bf16 GEMM (R3 lockstep structure, 39 us / 0 in-loop conflicts):
// C(2048 x 4096) = A(2048 x 2048) * Bt(4096 x 2048)^T.
// BM=256, BN=128, BK=64. 512 threads = 8 waves (4M x 2N, 64x64 each).
// 3 LDS buffers, stage tile t+2 each iter, counted vmcnt(6), raw s_barrier.
// XOR swizzle slot^(row&7) on both global source and ds_read addr (rule #21).
// gemm_plain: pure (no transpose code). gemm_tr: + transposed-output epilogue.
// ---------------------------------------------------------------------------
#define GK 2048      // K
#define GN 4096      // output cols
#define NT 32        // K / 64
#define BUFU 24576   // u16 per buffer: A 256*64=16384 + B 128*64=8192

#define GEMM_PREAMBLE                                                          \
  __shared__ u16 smem[3 * BUFU];                                               \
  int t = threadIdx.x, lane = t & 63, wave = t >> 6;                           \
  int lin = blockIdx.y * gridDim.x + blockIdx.x;                               \
  int nwg = gridDim.x * gridDim.y;                                             \
  int sw = (lin & 7) * (nwg >> 3) + (lin >> 3);                                \
  int bx = sw & 31, by = sw >> 5;                                              \
  int m0 = by * 256, n0 = bx * 128;                                            \
  const u16* pg[6];                                                            \
  int lof[6];                                                                  \
  _Pragma("unroll") for (int j = 0; j < 4; j++) {                              \
    int c = t + 512 * j;                                                       \
    int row = c >> 3;                                                          \
    int gs = (c & 7) ^ (row & 7);                                              \
    pg[j] = A + (size_t)(m0 + row) * GK + gs * 8;                              \
    lof[j] = c * 8;                                                            \
  }                                                                            \
  _Pragma("unroll") for (int j = 0; j < 2; j++) {                              \
    int c = t + 512 * j;                                                       \
    int row = c >> 3;                                                          \
    int gs = (c & 7) ^ (row & 7);                                              \
    pg[4 + j] = Bt + (size_t)(n0 + row) * GK + gs * 8;                         \
    lof[4 + j] = 16384 + c * 8;                                                \
  }                                                                            \
  auto stage = [&](int b, int kt) {                                            \
    _Pragma("unroll") for (int j = 0; j < 6; j++)                              \
        gload_lds16(pg[j] + kt, &smem[b * BUFU + lof[j]]);                     \
  };                                                                           \
  int wr = wave >> 1, wc = wave & 1;                                           \
  int lr = lane & 15, lg = lane >> 4;                                          \
  floatx4 acc[4][4];                                                           \
  _Pragma("unroll") for (int mi = 0; mi < 4; mi++)                             \
      _Pragma("unroll") for (int ni = 0; ni < 4; ni++)                         \
          acc[mi][ni] = (floatx4)0.0f;                                         \
  int aoff[2][4], boff[2][4];                                                  \
  _Pragma("unroll") for (int s = 0; s < 2; s++) {                              \
    _Pragma("unroll") for (int mi = 0; mi < 4; mi++) {                         \
      int row = wr * 64 + mi * 16 + lr;                                        \
      int slot = s * 4 + lg;                                                   \
      aoff[s][mi] = row * 64 + (slot ^ (row & 7)) * 8;                         \
    }                                                                          \
    _Pragma("unroll") for (int ni = 0; ni < 4; ni++) {                         \
      int row = wc * 64 + ni * 16 + lr;                                        \
      int slot = s * 4 + lg;                                                   \
      boff[s][ni] = 16384 + row * 64 + (slot ^ (row & 7)) * 8;                 \
    }                                                                          \
  }                                                                            \
  auto compute = [&](int b) {                                                  \
    const u16* base = &smem[b * BUFU];                                         \
    short8 af[2][4], bf[2][4];                                                 \
    _Pragma("unroll") for (int s = 0; s < 2; s++) {                            \
      _Pragma("unroll") for (int mi = 0; mi < 4; mi++)                         \
          af[s][mi] = *(const short8*)(base + aoff[s][mi]);                    \
      _Pragma("unroll") for (int ni = 0; ni < 4; ni++)                         \
          bf[s][ni] = *(const short8*)(base + boff[s][ni]);                    \
    }                                                                          \
    _Pragma("unroll") for (int s = 0; s < 2; s++)                              \
        _Pragma("unroll") for (int mi = 0; mi < 4; mi++)                       \
            _Pragma("unroll") for (int ni = 0; ni < 4; ni++)                   \
                acc[mi][ni] = __builtin_amdgcn_mfma_f32_16x16x32_bf16(         \
                    af[s][mi], bf[s][ni], acc[mi][ni], 0, 0, 0);               \
  };                                                                           \
  stage(0, 0);                                                                 \
  stage(1, 64);                                                                \
  for (int tt = 0; tt < NT - 2; ++tt) {                                        \
    asm volatile("s_waitcnt vmcnt(6)" ::: "memory");                           \
    __builtin_amdgcn_s_barrier();                                              \
    stage((tt + 2) % 3, (tt + 2) * 64);                                        \
    compute(tt % 3);                                                           \
  }                                                                            \
  asm volatile("s_waitcnt vmcnt(6)" ::: "memory");                             \
  __builtin_amdgcn_s_barrier();                                                \
  compute((NT - 2) % 3);                                                       \
  asm volatile("s_waitcnt vmcnt(0)" ::: "memory");                             \
  __builtin_amdgcn_s_barrier();                                                \
  compute((NT - 1) % 3);                                                       \
  _Pragma("unroll") for (int mi = 0; mi < 4; mi++)                             \
      _Pragma("unroll") for (int ni = 0; ni < 4; ni++) {                       \
    int row = m0 + wr * 64 + mi * 16 + lg * 4;                                 \
    int col = n0 + wc * 64 + ni * 16 + lr;                                     \
    _Pragma("unroll") for (int r = 0; r < 4; r++)                              \
        C[(size_t)(row + r) * GN + col] = f2bf(acc[mi][ni][r]);                \
  }

__global__ __launch_bounds__(512) void gemm_plain(const u16* __restrict__ A,
                                                  const u16* __restrict__ Bt,
                                                  u16* __restrict__ C) {
  GEMM_PREAMBLE
}

__global__ __launch_bounds__(512) void gemm_tr(const u16* __restrict__ A,
                                               const u16* __restrict__ Bt,
                                               u16* __restrict__ C,
                                               u16* __restrict__ Ct) {
  GEMM_PREAMBLE
  // ---- transposed epilogue: Ct[col][row], per-wave stride-72 LDS scratch.
  // Row start bank = (c*36)%32 spreads consecutive lanes; write 8B and read
  // 16B phases are <=2-way (free) without any XOR.
  __syncthreads();  // all waves done reading the pipeline buffers
  u16* scr = smem + wave * 4608;  // 64 rows * 72 u16 = 9216B per wave
#pragma unroll
  for (int mi = 0; mi < 4; mi++)
#pragma unroll
    for (int ni = 0; ni < 4; ni++) {
      int ncol = ni * 16 + lr;
      // mrow = chunk*8 + (lg&1)*4 + r == mi*16 + lg*4 + r
      int chunk = mi * 2 + (lg >> 1);
      int off = ncol * 72 + chunk * 8 + (lg & 1) * 4;
      short4v sv;
#pragma unroll
      for (int r = 0; r < 4; r++) sv[r] = (short)f2bf(acc[mi][ni][r]);
      *(short4v*)&scr[off] = sv;
    }
  int c = lane;
  u16* op = Ct + (size_t)(n0 + wc * 64 + c) * GK + m0 + wr * 64;
#pragma unroll
  for (int jj = 0; jj < 8; jj++) {
    short8 v = *(const short8*)&scr[c * 72 + jj * 8];
    *(short8*)(op + jj * 8) = v;
  }
}

// ---------------------------------------------------------------------------
// Final per-node fused GEMM: out[b,n,o] = sum_kk A[b,kk]*Weff[n,kk,o] + bias[n,o]
// W arrives in native node-major [kk][o] order (kk = k*64+i); staged into a
// swizzled [o][slot] LDS layout: element (kk,o) at Ws[o*200 + ((kk>>3)^(o>>3))*8
// + (kk&7)]. Scatter writes <=2-way conflicts; b128 frag reads conflict-free
// and 16B-aligned (kk multiple of 8 in the MFMA loop).
// ---------------------------------------------------------------------------
__global__ __launch_bounds__(256) void final_k(const float* __restrict__ x,
                                               const float* __restrict__ E,
                                               const float* __restrict__ bpool,
                                               const u16* __restrict__ xg1,
                                               const u16* __restrict__ xg2,
                                               const u16* __restrict__ W,
                                               float* __restrict__ out) {
  __shared__ u16 Xs[3][64][72];   // [k][b][i], +8 pad: 2-way banks only
  __shared__ u16 Ws[64 * 200];    // [o][swizzled kk], see header comment
  __shared__ float bias_s[64];
  int n = blockIdx.x, t = threadIdx.x;

  {  // stage k=0 slab from fp32 x
    int b = t >> 2, i0 = (t & 3) * 16;
    const float* xp = x + ((size_t)b * NNODES + n) * DIN + i0;
    float4 v0 = ((const float4*)xp)[0];
    float4 v1 = ((const float4*)xp)[1];
    float4 v2 = ((const float4*)xp)[2];
    float4 v3 = ((const float4*)xp)[3];
    u16* d = &Xs[0][b][i0];
    d[0] = f2bf(v0.x); d[1] = f2bf(v0.y); d[2] = f2bf(v0.z); d[3] = f2bf(v0.w);
    d[4] = f2bf(v1.x); d[5] = f2bf(v1.y); d[6] = f2bf(v1.z); d[7] = f2bf(v1.w);
    d[8] = f2bf(v2.x); d[9] = f2bf(v2.y); d[10] = f2bf(v2.z); d[11] = f2bf(v2.w);
    d[12] = f2bf(v3.x); d[13] = f2bf(v3.y); d[14] = f2bf(v3.z); d[15] = f2bf(v3.w);
  }
  for (int idx = t; idx < 512; idx += 256) {  // k=1,2 slabs (rows of xg1/xg2)
    short8 v1 = *(const short8*)(xg1 + (size_t)n * 4096 + idx * 8);
    *(short8*)&Xs[1][idx >> 3][(idx & 7) * 8] = v1;
    short8 v2 = *(const short8*)(xg2 + (size_t)n * 4096 + idx * 8);
    *(short8*)&Xs[2][idx >> 3][(idx & 7) * 8] = v2;
  }
  for (int idx = t; idx < 1536; idx += 256) {  // W: native [kk][o] -> swizzled
    short8 v = *(const short8*)(W + (size_t)n * 12288 + idx * 8);
    int kk = idx >> 3;           // e' = idx*8 + j = kk*64 + (oo + j)
    int oo = (idx & 7) * 8;
    int c8 = kk >> 3, k7 = kk & 7;
#pragma unroll
    for (int j = 0; j < 8; j++) {
      int o = oo + j;
      Ws[o * 200 + ((c8 ^ (o >> 3)) << 3) + k7] = (u16)v[j];
    }
  }
  if (t < 64) {
    float acc = 0.0f;
#pragma unroll
    for (int d = 0; d < 16; d++)
      acc = fmaf(E[(size_t)n * EMB + d], bpool[d * 64 + t], acc);
    bias_s[t] = acc;
  }
  __syncthreads();

  int lane = t & 63, wave = t >> 6;
  int lr = lane & 15, lg = lane >> 4;
  int wb = wave * 16;
  floatx4 acc[4];
#pragma unroll
  for (int ot = 0; ot < 4; ot++) acc[ot] = (floatx4)0.0f;

#pragma unroll
  for (int ks = 0; ks < 6; ks++) {
    int kk = ks * 32 + lg * 8;           // multiple of 8
    int c8 = ks * 4 + lg;                // kk >> 3
    short8 a = *(const short8*)&Xs[kk >> 6][wb + lr][kk & 63];
#pragma unroll
    for (int ot = 0; ot < 4; ot++) {
      int o = ot * 16 + lr;
      short8 bb = *(const short8*)&Ws[o * 200 + ((c8 ^ (o >> 3)) << 3)];
      acc[ot] = __builtin_amdgcn_mfma_f32_16x16x32_bf16(a, bb, acc[ot], 0, 0, 0);
    }
  }
#pragma unroll
  for (int ot = 0; ot < 4; ot++) {
    int o = ot * 16 + lr;
    float bs = bias_s[o];
#pragma unroll
    for (int r = 0; r < 4; r++) {
      int b = wb + lg * 4 + r;
      out[((size_t)b * NNODES + n) * DOUT + o] = acc[ot][r] + bs;
    }
  }
}

// ---------------------------------------------------------------------------
extern "C" void kernel_launch(void* const* d_in, const int* in_sizes, int n_in,
                              void* d_out, int out_size, void* d_ws, size_t ws_size,
                              hipStream_t stream) {
  const float* x     = (const float*)d_in[0];  // (64,2048,64)
  const float* E     = (const float*)d_in[1];  // (2048,16)
  const float* pool  = (const float*)d_in[2];  // (16,3,64,64)
  const float* bpool = (const float*)d_in[3];  // (16,64)
  float* out = (float*)d_out;

  char* ws = (char*)d_ws;
  u16* Sb   = (u16*)(ws);                    // 2048*2048*2  = 8 MiB
  u16* xtt  = (u16*)(ws + 8388608);          // 4096*2048*2  = 16 MiB
  u16* xg1  = (u16*)(ws + 25165824);         // 2048*4096*2
  u16* xg1t = (u16*)(ws + 41943040);         // 4096*2048*2
  u16* xg2  = (u16*)(ws + 58720256);         // 2048*4096*2
  u16* Wall = (u16*)(ws + 75497472);         // 2048*12288*2 = 48 MiB  (end 120 MiB)

  // fused: wgen-native (768) + adj_softmax (2048) + trans_x (2048)
  prologue<<<4864, 256, 0, stream>>>(E, pool, x, Sb, xtt, Wall);
  // xg1[n][b*64+c] = sum_m S[n][m] * x[b][m][c]; also emits xg1t = xg1^T
  gemm_tr<<<dim3(32, 8), 512, 0, stream>>>(Sb, xtt, xg1, xg1t);
  // xg2[n][bc] = sum_m S[n][m] * xg1[m][bc]   (un-scaled; T2 folded into Weff)
  gemm_plain<<<dim3(32, 8), 512, 0, stream>>>(Sb, xg1t, xg2);
  final_k<<<NNODES, 256, 0, stream>>>(x, E, bpool, xg1, xg2, Wall, out);
}

// Round 8
// 146.197 us; speedup vs baseline: 1.6544x; 1.0581x over previous
//
#include <hip/hip_runtime.h>
#include <hip/hip_bf16.h>

typedef unsigned short u16;
typedef short short8 __attribute__((ext_vector_type(8)));
typedef short short4v __attribute__((ext_vector_type(4)));
typedef float floatx4 __attribute__((ext_vector_type(4)));

#define NNODES 2048
#define BATCH  64
#define DIN    64
#define DOUT   64
#define EMB    16

__device__ __forceinline__ u16 f2bf(float f) {
  union { float f; unsigned u; } v; v.f = f;
  unsigned r = v.u + 0x7fffu + ((v.u >> 16) & 1u);
  return (u16)(r >> 16);
}

__device__ __forceinline__ void gload_lds16(const void* g, void* l) {
  __builtin_amdgcn_global_load_lds(
      (const __attribute__((address_space(1))) void*)g,
      (__attribute__((address_space(3))) void*)l, 16, 0, 0);
}

// ---------------------------------------------------------------------------
// Fused prologue: three independent input-only jobs in one dispatch.
//   blocks [0,768):     wgen (native layout)  -> Wall   (heaviest: first)
//   blocks [768,2816):  adj_softmax row n     -> Sb
//   blocks [2816,4864): trans_x tile          -> xtt
// wgen: W[n][e'] = sum_d E[n][d]*pool_eff[d][e'], e' = k*4096+i*64+o (native).
// E row is read DIRECTLY with a wave-uniform address -> compiler emits s_load
// (scalar cache), NOT via LDS. The previous Es-in-LDS staging cost 2048
// ds_read_b32 per wave (16 x 128 nodes) and serialized the per-CU LDS pipe:
// ~59 us modeled, 53 us measured (R7). v_fma reads the SGPR operand directly.
// ---------------------------------------------------------------------------
__global__ __launch_bounds__(256) void prologue(const float* __restrict__ E,
                                                const float* __restrict__ pool,
                                                const float* __restrict__ x,
                                                u16* __restrict__ Sb,
                                                u16* __restrict__ xtt,
                                                u16* __restrict__ W) {
  int bid = blockIdx.x;
  int t = threadIdx.x;

  if (bid < 768) {
    // ---- weight generation, native (k,i,o) order, E via scalar loads ----
    int ec = bid % 48, nc = bid / 48;
    int e = ec * 256 + t;            // e' = k*4096 + i*64 + o
    int n0 = nc * 128;
    float pv[16];
#pragma unroll
    for (int d = 0; d < 16; d++) {
      float p = pool[(size_t)d * 12288 + e];
      if (e < 4096) p -= pool[(size_t)d * 12288 + 8192 + e];
      if (e >= 8192) p += p;
      pv[d] = p;
    }
    const float* er = E + (size_t)n0 * EMB;   // wave-uniform base
#pragma unroll 4
    for (int nn = 0; nn < 128; nn++) {
      float acc = 0.0f;
#pragma unroll
      for (int d = 0; d < 16; d++) acc = fmaf(er[nn * EMB + d], pv[d], acc);
      W[(size_t)(n0 + nn) * 12288 + e] = f2bf(acc);
    }

  } else if (bid < 2816) {
    // ---- S = softmax(relu(E E^T)) row n, bf16 out ----
    int n = bid - 768;
    const float4* ep = (const float4*)(E + (size_t)n * EMB);
    float4 e0 = ep[0], e1 = ep[1], e2 = ep[2], e3 = ep[3];
    float lg[8];
    float mx = 0.0f;  // relu => all logits >= 0
#pragma unroll
    for (int j = 0; j < 8; j++) {
      int m = t + j * 256;
      const float4* mp = (const float4*)(E + (size_t)m * EMB);
      float4 a = mp[0], b = mp[1], c = mp[2], d = mp[3];
      float dot = e0.x * a.x + e0.y * a.y + e0.z * a.z + e0.w * a.w
                + e1.x * b.x + e1.y * b.y + e1.z * b.z + e1.w * b.w
                + e2.x * c.x + e2.y * c.y + e2.z * c.z + e2.w * c.w
                + e3.x * d.x + e3.y * d.y + e3.z * d.z + e3.w * d.w;
      dot = fmaxf(dot, 0.0f);
      lg[j] = dot;
      mx = fmaxf(mx, dot);
    }
    __shared__ float smax[4], ssum[4];
#pragma unroll
    for (int off = 32; off > 0; off >>= 1) mx = fmaxf(mx, __shfl_xor(mx, off, 64));
    if ((t & 63) == 0) smax[t >> 6] = mx;
    __syncthreads();
    mx = fmaxf(fmaxf(smax[0], smax[1]), fmaxf(smax[2], smax[3]));
    float sum = 0.0f;
#pragma unroll
    for (int j = 0; j < 8; j++) {
      float e = __expf(lg[j] - mx);
      lg[j] = e;
      sum += e;
    }
#pragma unroll
    for (int off = 32; off > 0; off >>= 1) sum += __shfl_xor(sum, off, 64);
    if ((t & 63) == 0) ssum[t >> 6] = sum;
    __syncthreads();
    sum = ssum[0] + ssum[1] + ssum[2] + ssum[3];
    float inv = 1.0f / sum;
#pragma unroll
    for (int j = 0; j < 8; j++)
      Sb[(size_t)n * NNODES + t + j * 256] = f2bf(lg[j] * inv);

  } else {
    // ---- x (B,N,DIN) f32 -> xtt (B*64+c, N) bf16 ----
    __shared__ float tile[64][68];
    int u = bid - 2816;
    int b = u >> 5;
    int m0 = (u & 31) * 64;
    int r = t >> 2, cs = (t & 3) * 16;
    const float* xp = x + ((size_t)b * NNODES + m0 + r) * DIN + cs;
    float4 v0 = ((const float4*)xp)[0];
    float4 v1 = ((const float4*)xp)[1];
    float4 v2 = ((const float4*)xp)[2];
    float4 v3 = ((const float4*)xp)[3];
    *(float4*)&tile[r][cs]      = v0;
    *(float4*)&tile[r][cs + 4]  = v1;
    *(float4*)&tile[r][cs + 8]  = v2;
    *(float4*)&tile[r][cs + 12] = v3;
    __syncthreads();
    int c = t >> 2, ms = (t & 3) * 16;
    short8 o0, o1;
#pragma unroll
    for (int j = 0; j < 8; j++) o0[j] = (short)f2bf(tile[ms + j][c]);
#pragma unroll
    for (int j = 0; j < 8; j++) o1[j] = (short)f2bf(tile[ms + 8 + j][c]);
    u16* op = xtt + ((size_t)b * 64 + c) * NNODES + m0 + ms;
    *(short8*)op = o0;
    *(short8*)(op + 8) = o1;
  }
}

// ---------------------------------------------------------------------------
// Deep-pipelined bf16 GEMM (R3 lockstep structure, 39 us / 0 in-loop conflicts):
// C(2048 x 4096) = A(2048 x 2048) * Bt(4096 x 2048)^T.
// BM=256, BN=128, BK=64. 512 threads = 8 waves (4M x 2N, 64x64 each).
// 3 LDS buffers, stage tile t+2 each iter, counted vmcnt(6), raw s_barrier.
// XOR swizzle slot^(row&7) on both global source and ds_read addr (rule #21).
// gemm_plain: pure (no transpose code). gemm_tr: + transposed-output epilogue.
// ---------------------------------------------------------------------------
#define GK 2048      // K
#define GN 4096      // output cols
#define NT 32        // K / 64
#define BUFU 24576   // u16 per buffer: A 256*64=16384 + B 128*64=8192

#define GEMM_PREAMBLE                                                          \
  __shared__ u16 smem[3 * BUFU];                                               \
  int t = threadIdx.x, lane = t & 63, wave = t >> 6;                           \
  int lin = blockIdx.y * gridDim.x + blockIdx.x;                               \
  int nwg = gridDim.x * gridDim.y;                                             \
  int sw = (lin & 7) * (nwg >> 3) + (lin >> 3);                                \
  int bx = sw & 31, by = sw >> 5;                                              \
  int m0 = by * 256, n0 = bx * 128;                                            \
  const u16* pg[6];                                                            \
  int lof[6];                                                                  \
  _Pragma("unroll") for (int j = 0; j < 4; j++) {                              \
    int c = t + 512 * j;                                                       \
    int row = c >> 3;                                                          \
    int gs = (c & 7) ^ (row & 7);                                              \
    pg[j] = A + (size_t)(m0 + row) * GK + gs * 8;                              \
    lof[j] = c * 8;                                                            \
  }                                                                            \
  _Pragma("unroll") for (int j = 0; j < 2; j++) {                              \
    int c = t + 512 * j;                                                       \
    int row = c >> 3;                                                          \
    int gs = (c & 7) ^ (row & 7);                                              \
    pg[4 + j] = Bt + (size_t)(n0 + row) * GK + gs * 8;                         \
    lof[4 + j] = 16384 + c * 8;                                                \
  }                                                                            \
  auto stage = [&](int b, int kt) {                                            \
    _Pragma("unroll") for (int j = 0; j < 6; j++)                              \
        gload_lds16(pg[j] + kt, &smem[b * BUFU + lof[j]]);                     \
  };                                                                           \
  int wr = wave >> 1, wc = wave & 1;                                           \
  int lr = lane & 15, lg = lane >> 4;                                          \
  floatx4 acc[4][4];                                                           \
  _Pragma("unroll") for (int mi = 0; mi < 4; mi++)                             \
      _Pragma("unroll") for (int ni = 0; ni < 4; ni++)                         \
          acc[mi][ni] = (floatx4)0.0f;                                         \
  int aoff[2][4], boff[2][4];                                                  \
  _Pragma("unroll") for (int s = 0; s < 2; s++) {                              \
    _Pragma("unroll") for (int mi = 0; mi < 4; mi++) {                         \
      int row = wr * 64 + mi * 16 + lr;                                        \
      int slot = s * 4 + lg;                                                   \
      aoff[s][mi] = row * 64 + (slot ^ (row & 7)) * 8;                         \
    }                                                                          \
    _Pragma("unroll") for (int ni = 0; ni < 4; ni++) {                         \
      int row = wc * 64 + ni * 16 + lr;                                        \
      int slot = s * 4 + lg;                                                   \
      boff[s][ni] = 16384 + row * 64 + (slot ^ (row & 7)) * 8;                 \
    }                                                                          \
  }                                                                            \
  auto compute = [&](int b) {                                                  \
    const u16* base = &smem[b * BUFU];                                         \
    short8 af[2][4], bf[2][4];                                                 \
    _Pragma("unroll") for (int s = 0; s < 2; s++) {                            \
      _Pragma("unroll") for (int mi = 0; mi < 4; mi++)                         \
          af[s][mi] = *(const short8*)(base + aoff[s][mi]);                    \
      _Pragma("unroll") for (int ni = 0; ni < 4; ni++)                         \
          bf[s][ni] = *(const short8*)(base + boff[s][ni]);                    \
    }                                                                          \
    _Pragma("unroll") for (int s = 0; s < 2; s++)                              \
        _Pragma("unroll") for (int mi = 0; mi < 4; mi++)                       \
            _Pragma("unroll") for (int ni = 0; ni < 4; ni++)                   \
                acc[mi][ni] = __builtin_amdgcn_mfma_f32_16x16x32_bf16(         \
                    af[s][mi], bf[s][ni], acc[mi][ni], 0, 0, 0);               \
  };                                                                           \
  stage(0, 0);                                                                 \
  stage(1, 64);                                                                \
  for (int tt = 0; tt < NT - 2; ++tt) {                                        \
    asm volatile("s_waitcnt vmcnt(6)" ::: "memory");                           \
    __builtin_amdgcn_s_barrier();                                              \
    stage((tt + 2) % 3, (tt + 2) * 64);                                        \
    compute(tt % 3);                                                           \
  }                                                                            \
  asm volatile("s_waitcnt vmcnt(6)" ::: "memory");                             \
  __builtin_amdgcn_s_barrier();                                                \
  compute((NT - 2) % 3);                                                       \
  asm volatile("s_waitcnt vmcnt(0)" ::: "memory");                             \
  __builtin_amdgcn_s_barrier();                                                \
  compute((NT - 1) % 3);                                                       \
  _Pragma("unroll") for (int mi = 0; mi < 4; mi++)                             \
      _Pragma("unroll") for (int ni = 0; ni < 4; ni++) {                       \
    int row = m0 + wr * 64 + mi * 16 + lg * 4;                                 \
    int col = n0 + wc * 64 + ni * 16 + lr;                                     \
    _Pragma("unroll") for (int r = 0; r < 4; r++)                              \
        C[(size_t)(row + r) * GN + col] = f2bf(acc[mi][ni][r]);                \
  }

__global__ __launch_bounds__(512) void gemm_plain(const u16* __restrict__ A,
                                                  const u16* __restrict__ Bt,
                                                  u16* __restrict__ C) {
  GEMM_PREAMBLE
}

__global__ __launch_bounds__(512) void gemm_tr(const u16* __restrict__ A,
                                               const u16* __restrict__ Bt,
                                               u16* __restrict__ C,
                                               u16* __restrict__ Ct) {
  GEMM_PREAMBLE
  // ---- transposed epilogue: Ct[col][row], per-wave stride-72 LDS scratch.
  // Row start bank = (c*36)%32 spreads consecutive lanes; write 8B and read
  // 16B phases are <=2-way (free) without any XOR.
  __syncthreads();  // all waves done reading the pipeline buffers
  u16* scr = smem + wave * 4608;  // 64 rows * 72 u16 = 9216B per wave
#pragma unroll
  for (int mi = 0; mi < 4; mi++)
#pragma unroll
    for (int ni = 0; ni < 4; ni++) {
      int ncol = ni * 16 + lr;
      // mrow = chunk*8 + (lg&1)*4 + r == mi*16 + lg*4 + r
      int chunk = mi * 2 + (lg >> 1);
      int off = ncol * 72 + chunk * 8 + (lg & 1) * 4;
      short4v sv;
#pragma unroll
      for (int r = 0; r < 4; r++) sv[r] = (short)f2bf(acc[mi][ni][r]);
      *(short4v*)&scr[off] = sv;
    }
  int c = lane;
  u16* op = Ct + (size_t)(n0 + wc * 64 + c) * GK + m0 + wr * 64;
#pragma unroll
  for (int jj = 0; jj < 8; jj++) {
    short8 v = *(const short8*)&scr[c * 72 + jj * 8];
    *(short8*)(op + jj * 8) = v;
  }
}

// ---------------------------------------------------------------------------
// Final per-node fused GEMM: out[b,n,o] = sum_kk A[b,kk]*Weff[n,kk,o] + bias[n,o]
// W arrives in native node-major [kk][o] order (kk = k*64+i); staged into a
// swizzled [o][slot] LDS layout: element (kk,o) at Ws[o*200 + ((kk>>3)^(o>>3))*8
// + (kk&7)]. Scatter writes <=2-way conflicts; b128 frag reads conflict-free
// and 16B-aligned (kk multiple of 8 in the MFMA loop).
// ---------------------------------------------------------------------------
__global__ __launch_bounds__(256) void final_k(const float* __restrict__ x,
                                               const float* __restrict__ E,
                                               const float* __restrict__ bpool,
                                               const u16* __restrict__ xg1,
                                               const u16* __restrict__ xg2,
                                               const u16* __restrict__ W,
                                               float* __restrict__ out) {
  __shared__ u16 Xs[3][64][72];   // [k][b][i], +8 pad: 2-way banks only
  __shared__ u16 Ws[64 * 200];    // [o][swizzled kk], see header comment
  __shared__ float bias_s[64];
  int n = blockIdx.x, t = threadIdx.x;

  {  // stage k=0 slab from fp32 x
    int b = t >> 2, i0 = (t & 3) * 16;
    const float* xp = x + ((size_t)b * NNODES + n) * DIN + i0;
    float4 v0 = ((const float4*)xp)[0];
    float4 v1 = ((const float4*)xp)[1];
    float4 v2 = ((const float4*)xp)[2];
    float4 v3 = ((const float4*)xp)[3];
    u16* d = &Xs[0][b][i0];
    d[0] = f2bf(v0.x); d[1] = f2bf(v0.y); d[2] = f2bf(v0.z); d[3] = f2bf(v0.w);
    d[4] = f2bf(v1.x); d[5] = f2bf(v1.y); d[6] = f2bf(v1.z); d[7] = f2bf(v1.w);
    d[8] = f2bf(v2.x); d[9] = f2bf(v2.y); d[10] = f2bf(v2.z); d[11] = f2bf(v2.w);
    d[12] = f2bf(v3.x); d[13] = f2bf(v3.y); d[14] = f2bf(v3.z); d[15] = f2bf(v3.w);
  }
  for (int idx = t; idx < 512; idx += 256) {  // k=1,2 slabs (rows of xg1/xg2)
    short8 v1 = *(const short8*)(xg1 + (size_t)n * 4096 + idx * 8);
    *(short8*)&Xs[1][idx >> 3][(idx & 7) * 8] = v1;
    short8 v2 = *(const short8*)(xg2 + (size_t)n * 4096 + idx * 8);
    *(short8*)&Xs[2][idx >> 3][(idx & 7) * 8] = v2;
  }
  for (int idx = t; idx < 1536; idx += 256) {  // W: native [kk][o] -> swizzled
    short8 v = *(const short8*)(W + (size_t)n * 12288 + idx * 8);
    int kk = idx >> 3;           // e' = idx*8 + j = kk*64 + (oo + j)
    int oo = (idx & 7) * 8;
    int c8 = kk >> 3, k7 = kk & 7;
#pragma unroll
    for (int j = 0; j < 8; j++) {
      int o = oo + j;
      Ws[o * 200 + ((c8 ^ (o >> 3)) << 3) + k7] = (u16)v[j];
    }
  }
  if (t < 64) {
    float acc = 0.0f;
#pragma unroll
    for (int d = 0; d < 16; d++)
      acc = fmaf(E[(size_t)n * EMB + d], bpool[d * 64 + t], acc);
    bias_s[t] = acc;
  }
  __syncthreads();

  int lane = t & 63, wave = t >> 6;
  int lr = lane & 15, lg = lane >> 4;
  int wb = wave * 16;
  floatx4 acc[4];
#pragma unroll
  for (int ot = 0; ot < 4; ot++) acc[ot] = (floatx4)0.0f;

#pragma unroll
  for (int ks = 0; ks < 6; ks++) {
    int kk = ks * 32 + lg * 8;           // multiple of 8
    int c8 = ks * 4 + lg;                // kk >> 3
    short8 a = *(const short8*)&Xs[kk >> 6][wb + lr][kk & 63];
#pragma unroll
    for (int ot = 0; ot < 4; ot++) {
      int o = ot * 16 + lr;
      short8 bb = *(const short8*)&Ws[o * 200 + ((c8 ^ (o >> 3)) << 3)];
      acc[ot] = __builtin_amdgcn_mfma_f32_16x16x32_bf16(a, bb, acc[ot], 0, 0, 0);
    }
  }
#pragma unroll
  for (int ot = 0; ot < 4; ot++) {
    int o = ot * 16 + lr;
    float bs = bias_s[o];
#pragma unroll
    for (int r = 0; r < 4; r++) {
      int b = wb + lg * 4 + r;
      out[((size_t)b * NNODES + n) * DOUT + o] = acc[ot][r] + bs;
    }
  }
}

// ---------------------------------------------------------------------------
extern "C" void kernel_launch(void* const* d_in, const int* in_sizes, int n_in,
                              void* d_out, int out_size, void* d_ws, size_t ws_size,
                              hipStream_t stream) {
  const float* x     = (const float*)d_in[0];  // (64,2048,64)
  const float* E     = (const float*)d_in[1];  // (2048,16)
  const float* pool  = (const float*)d_in[2];  // (16,3,64,64)
  const float* bpool = (const float*)d_in[3];  // (16,64)
  float* out = (float*)d_out;

  char* ws = (char*)d_ws;
  u16* Sb   = (u16*)(ws);                    // 2048*2048*2  = 8 MiB
  u16* xtt  = (u16*)(ws + 8388608);          // 4096*2048*2  = 16 MiB
  u16* xg1  = (u16*)(ws + 25165824);         // 2048*4096*2
  u16* xg1t = (u16*)(ws + 41943040);         // 4096*2048*2
  u16* xg2  = (u16*)(ws + 58720256);         // 2048*4096*2
  u16* Wall = (u16*)(ws + 75497472);         // 2048*12288*2 = 48 MiB  (end 120 MiB)

  // fused: wgen-native (768) + adj_softmax (2048) + trans_x (2048)
  prologue<<<4864, 256, 0, stream>>>(E, pool, x, Sb, xtt, Wall);
  // xg1[n][b*64+c] = sum_m S[n][m] * x[b][m][c]; also emits xg1t = xg1^T
  gemm_tr<<<dim3(32, 8), 512, 0, stream>>>(Sb, xtt, xg1, xg1t);
  // xg2[n][bc] = sum_m S[n][m] * xg1[m][bc]   (un-scaled; T2 folded into Weff)
  gemm_plain<<<dim3(32, 8), 512, 0, stream>>>(Sb, xg1t, xg2);
  final_k<<<NNODES, 256, 0, stream>>>(x, E, bpool, xg1, xg2, Wall, out);
}